// Round 8
// baseline (1434.462 us; speedup 1.0000x reference)
//
#include <hip/hip_runtime.h>
#include <math.h>

// Problem constants (from reference)
#define Bb    2
#define Ss    1024
#define HIDd  2048
#define NHh   16
#define HDd   128
#define SBc   20      // floor(0.02*1024+0.5)
#define SELBc 61      // floor(0.06*1024+0.5)
#define RBc   82      // floor(0.08*1024+0.5)
#define CBc   163     // SB+SELB+RB
#define FFf   0.9f
#define MASKVAL (-3.4028234663852886e38f)
#define NBH   (Bb*NHh)       // 32
#define NROWS (NBH*Ss)       // 32768

typedef __attribute__((ext_vector_type(8))) short short8;
typedef __attribute__((ext_vector_type(4))) float f32x4;

__device__ __forceinline__ unsigned short f2b(float f) {
    unsigned u = __float_as_uint(f);
    u = (u + 0x7FFFu + ((u >> 16) & 1u)) >> 16;   // RNE
    return (unsigned short)u;
}
__device__ __forceinline__ float b2f(unsigned short h) {
    return __uint_as_float((unsigned)h << 16);
}

// ---------------------------------------------------------------------------
// Async global->LDS direct DMA (16B/lane). LDS dest = wave-uniform base +
// lane*16 (hardware rule); all call sites below have tid-linear LDS layouts.
// ---------------------------------------------------------------------------
#if defined(__has_builtin)
#if __has_builtin(__builtin_amdgcn_global_load_lds)
#define USE_GLD 1
#endif
#endif

__device__ __forceinline__ void gload16(const void* g, void* l) {
#ifdef USE_GLD
    __builtin_amdgcn_global_load_lds(
        (const __attribute__((address_space(1))) void*)g,
        (__attribute__((address_space(3))) void*)l, 16, 0, 0);
#else
    *(short8*)l = *(const short8*)g;
#endif
}

// ---------------------------------------------------------------------------
// fp32 -> split bf16 (hi + lo). lo = bf16(x - fp32(hi)).
// ---------------------------------------------------------------------------
__global__ __launch_bounds__(256) void conv_split(const float* __restrict__ x,
                                                  unsigned short* __restrict__ yh,
                                                  unsigned short* __restrict__ yl, int n4)
{
    int i = blockIdx.x * 256 + threadIdx.x;
    if (i >= n4) return;
    float4 v = ((const float4*)x)[i];
    ushort4 h, l;
    h.x = f2b(v.x); l.x = f2b(v.x - b2f(h.x));
    h.y = f2b(v.y); l.y = f2b(v.y - b2f(h.y));
    h.z = f2b(v.z); l.z = f2b(v.z - b2f(h.z));
    h.w = f2b(v.w); l.w = f2b(v.w - b2f(h.w));
    ((ushort4*)yh)[i] = h;
    ((ushort4*)yl)[i] = l;
}

// ---------------------------------------------------------------------------
// Merged weight transpose/convert: z=0: wq->split, z=1: wk->split,
// z=2: wv->single, z=3: wo->single. W[k][n] fp32 -> Wt[n][k] bf16.
// ---------------------------------------------------------------------------
__global__ __launch_bounds__(256) void tconv_all(const float* __restrict__ wq,
                                                 const float* __restrict__ wk,
                                                 const float* __restrict__ wv,
                                                 const float* __restrict__ wo,
                                                 unsigned short* __restrict__ wqth,
                                                 unsigned short* __restrict__ wqtl,
                                                 unsigned short* __restrict__ wkth,
                                                 unsigned short* __restrict__ wktl,
                                                 unsigned short* __restrict__ wvt,
                                                 unsigned short* __restrict__ wot)
{
    __shared__ float T[64][65];
    const int z = blockIdx.z;
    const float* W = (z == 0) ? wq : (z == 1) ? wk : (z == 2) ? wv : wo;
    int n0 = blockIdx.x * 64, k0 = blockIdx.y * 64;
    int tid = threadIdx.x;
    int rr = tid >> 4, cc = (tid & 15) * 4;
#pragma unroll
    for (int p = 0; p < 4; ++p) {
        int r = rr + p * 16;
        float4 x = *(const float4*)&W[(size_t)(k0 + r) * HIDd + n0 + cc];
        T[r][cc] = x.x; T[r][cc + 1] = x.y; T[r][cc + 2] = x.z; T[r][cc + 3] = x.w;
    }
    __syncthreads();
    if (z < 2) {
        unsigned short* Wth = z ? wkth : wqth;
        unsigned short* Wtl = z ? wktl : wqtl;
#pragma unroll
        for (int p = 0; p < 4; ++p) {
            int rn = rr + p * 16;
            float v0 = T[cc][rn], v1 = T[cc + 1][rn], v2 = T[cc + 2][rn], v3 = T[cc + 3][rn];
            ushort4 h, l;
            h.x = f2b(v0); l.x = f2b(v0 - b2f(h.x));
            h.y = f2b(v1); l.y = f2b(v1 - b2f(h.y));
            h.z = f2b(v2); l.z = f2b(v2 - b2f(h.z));
            h.w = f2b(v3); l.w = f2b(v3 - b2f(h.w));
            *(ushort4*)&Wth[(size_t)(n0 + rn) * HIDd + k0 + cc] = h;
            *(ushort4*)&Wtl[(size_t)(n0 + rn) * HIDd + k0 + cc] = l;
        }
    } else {
        unsigned short* Wt = (z == 2) ? wvt : wot;
#pragma unroll
        for (int p = 0; p < 4; ++p) {
            int rn = rr + p * 16;
            ushort4 o;
            o.x = f2b(T[cc][rn]);     o.y = f2b(T[cc + 1][rn]);
            o.z = f2b(T[cc + 2][rn]); o.w = f2b(T[cc + 3][rn]);
            *(ushort4*)&Wt[(size_t)(n0 + rn) * HIDd + k0 + cc] = o;
        }
    }
}

// ---------------------------------------------------------------------------
// Merged q/k/v projection GEMM with FUSED RoPE epilogue for q/k.
// Grid (48,16): region = blockIdx.x>>4 (0=q, 1=k, 2=v); 768 blocks.
// Each q/k block spans exactly one head (128 cols), so the RoPE (d, d+64)
// pair is intra-block: wc=64 waves park their acc in the (dead) staging LDS,
// wc=0 waves combine, apply the IDENTICAL powf/cosf/sinf expressions the old
// rope kernel used, split-convert, and store qh/ql (kh/kl) directly.
// Eliminates the rope kernel + the qf/kf fp32 round trip. Bit-identical.
// ---------------------------------------------------------------------------
__global__ __launch_bounds__(256) void gemm_qkv(const unsigned short* __restrict__ hsh,
                                                const unsigned short* __restrict__ hsl,
                                                const unsigned short* __restrict__ wqth,
                                                const unsigned short* __restrict__ wqtl,
                                                const unsigned short* __restrict__ wkth,
                                                const unsigned short* __restrict__ wktl,
                                                const unsigned short* __restrict__ wvt,
                                                unsigned short* __restrict__ qhp,
                                                unsigned short* __restrict__ qlp,
                                                unsigned short* __restrict__ khp,
                                                unsigned short* __restrict__ klp,
                                                float* __restrict__ vf)
{
    __shared__ unsigned short SM[4 * 128 * 32];   // staging; reused as RoPE LDS
    unsigned short* AsH = SM;
    unsigned short* AsL = SM + 128 * 32;
    unsigned short* BsH = SM + 2 * 128 * 32;
    unsigned short* BsL = SM + 3 * 128 * 32;
    const int tid = threadIdx.x;
    const int region = blockIdx.x >> 4;              // 0=q, 1=k, 2=v
    const int bn = (blockIdx.x & 15) * 128;
    const int bm = blockIdx.y * 128;
    const int K = HIDd;
    const int lane = tid & 63, wid = tid >> 6;
    const int wr = (wid >> 1) * 64, wc = (wid & 1) * 64;
    const int lm = lane & 15, lk = (lane >> 4) * 8;
    const int lr = (lane >> 4) * 4;

    f32x4 acc[4][4];
#pragma unroll
    for (int mi = 0; mi < 4; ++mi)
#pragma unroll
        for (int ni = 0; ni < 4; ++ni) acc[mi][ni] = 0.0f;

    if (region < 2) {
        const unsigned short* Bh = region ? wkth : wqth;
        const unsigned short* Bl = region ? wktl : wqtl;
        for (int k0 = 0; k0 < K; k0 += 32) {
#pragma unroll
            for (int l = 0; l < 2; ++l) {
                int L = tid + l * 256;
                int row = L >> 2, c8 = (L & 3) * 8;
                size_t ga = (size_t)(bm + row) * K + k0 + c8;
                size_t gb = (size_t)(bn + row) * K + k0 + c8;
                gload16(&hsh[ga], &AsH[L * 8]);
                gload16(&hsl[ga], &AsL[L * 8]);
                gload16(&Bh[gb], &BsH[L * 8]);
                gload16(&Bl[gb], &BsL[L * 8]);
            }
            __syncthreads();
            short8 ah[4], al[4], bh[4], bl[4];
#pragma unroll
            for (int mi = 0; mi < 4; ++mi) {
                ah[mi] = *(short8*)&AsH[(wr + mi * 16 + lm) * 32 + lk];
                al[mi] = *(short8*)&AsL[(wr + mi * 16 + lm) * 32 + lk];
            }
#pragma unroll
            for (int ni = 0; ni < 4; ++ni) {
                bh[ni] = *(short8*)&BsH[(wc + ni * 16 + lm) * 32 + lk];
                bl[ni] = *(short8*)&BsL[(wc + ni * 16 + lm) * 32 + lk];
            }
#pragma unroll
            for (int mi = 0; mi < 4; ++mi)
#pragma unroll
                for (int ni = 0; ni < 4; ++ni) {
                    acc[mi][ni] = __builtin_amdgcn_mfma_f32_16x16x32_bf16(ah[mi], bh[ni], acc[mi][ni], 0, 0, 0);
                    acc[mi][ni] = __builtin_amdgcn_mfma_f32_16x16x32_bf16(ah[mi], bl[ni], acc[mi][ni], 0, 0, 0);
                    acc[mi][ni] = __builtin_amdgcn_mfma_f32_16x16x32_bf16(al[mi], bh[ni], acc[mi][ni], 0, 0, 0);
                }
            __syncthreads();
        }
        // ---- fused RoPE epilogue ----
        unsigned short* Ho = region ? khp : qhp;
        unsigned short* Lo = region ? klp : qlp;
        float* Lx = (float*)SM;    // 128 rows x 64 cols fp32 = 32 KB
        if (wc) {                  // d in [64,128): park q2 values
#pragma unroll
            for (int mi = 0; mi < 4; ++mi)
#pragma unroll
                for (int ni = 0; ni < 4; ++ni)
#pragma unroll
                    for (int r = 0; r < 4; ++r) {
                        int row = wr + mi * 16 + lr + r;
                        int dc = ni * 16 + lm;      // d - 64
                        Lx[row * 64 + dc] = acc[mi][ni][r];
                    }
        }
        __syncthreads();
        if (!wc) {                 // d in [0,64): combine + RoPE + split store
            float invt[4];
#pragma unroll
            for (int ni = 0; ni < 4; ++ni) {
                int d = ni * 16 + lm;
                invt[ni] = powf(10000.0f, -2.0f * (float)d / 128.0f);
            }
            const int hh = bn >> 7;   // head index
#pragma unroll
            for (int mi = 0; mi < 4; ++mi)
#pragma unroll
                for (int r = 0; r < 4; ++r) {
                    int row = wr + mi * 16 + lr + r;
                    int m = bm + row;
                    int b_ = m >> 10, s_ = m & (Ss - 1);
                    size_t gb = ((size_t)(b_ * NHh + hh) * Ss + s_) * HDd;
#pragma unroll
                    for (int ni = 0; ni < 4; ++ni) {
                        int d = ni * 16 + lm;
                        float q1 = acc[mi][ni][r];
                        float q2 = Lx[row * 64 + d];
                        float fr = (float)s_ * invt[ni];
                        float c = cosf(fr), sn = sinf(fr);
                        float qa  = q1 * c - q2 * sn;
                        float qbv = q2 * c + q1 * sn;
                        unsigned short h;
                        h = f2b(qa);  Ho[gb + d]      = h; Lo[gb + d]      = f2b(qa  - b2f(h));
                        h = f2b(qbv); Ho[gb + d + 64] = h; Lo[gb + d + 64] = f2b(qbv - b2f(h));
                    }
                }
        }
    } else {
        for (int k0 = 0; k0 < K; k0 += 32) {
#pragma unroll
            for (int l = 0; l < 2; ++l) {
                int L = tid + l * 256;
                int row = L >> 2, c8 = (L & 3) * 8;
                gload16(&hsh[(size_t)(bm + row) * K + k0 + c8], &AsH[L * 8]);
                gload16(&wvt[(size_t)(bn + row) * K + k0 + c8], &BsH[L * 8]);
            }
            __syncthreads();
            short8 af[4], bf[4];
#pragma unroll
            for (int mi = 0; mi < 4; ++mi) af[mi] = *(short8*)&AsH[(wr + mi * 16 + lm) * 32 + lk];
#pragma unroll
            for (int ni = 0; ni < 4; ++ni) bf[ni] = *(short8*)&BsH[(wc + ni * 16 + lm) * 32 + lk];
#pragma unroll
            for (int mi = 0; mi < 4; ++mi)
#pragma unroll
                for (int ni = 0; ni < 4; ++ni)
                    acc[mi][ni] = __builtin_amdgcn_mfma_f32_16x16x32_bf16(af[mi], bf[ni], acc[mi][ni], 0, 0, 0);
            __syncthreads();
        }
#pragma unroll
        for (int mi = 0; mi < 4; ++mi)
#pragma unroll
            for (int ni = 0; ni < 4; ++ni)
#pragma unroll
                for (int r = 0; r < 4; ++r) {
                    int m = bm + wr + mi * 16 + lr + r;
                    int n = bn + wc + ni * 16 + lm;
                    int b_ = m / Ss, s_ = m % Ss;
                    int h_ = n / HDd, d_ = n % HDd;
                    vf[(size_t)((b_ * NHh + h_) * Ss + s_) * HDd + d_] = acc[mi][ni][r];
                }
    }
}

// ---------------------------------------------------------------------------
// Single-bf16 MFMA GEMM (wo): C = A @ Bt^T, plain [m][n] output.
// ---------------------------------------------------------------------------
__global__ __launch_bounds__(256) void gemm_bf16t(const unsigned short* __restrict__ A,
                                                  const unsigned short* __restrict__ Bt,
                                                  float* __restrict__ C,
                                                  int M, int N, int K)
{
    __shared__ unsigned short As[128 * 32];
    __shared__ unsigned short Bs[128 * 32];
    const int tid = threadIdx.x;
    const int bm = blockIdx.y * 128, bn = blockIdx.x * 128;
    const int lane = tid & 63, wid = tid >> 6;
    const int wr = (wid >> 1) * 64, wc = (wid & 1) * 64;
    const int lm = lane & 15, lk = (lane >> 4) * 8;

    f32x4 acc[4][4];
#pragma unroll
    for (int mi = 0; mi < 4; ++mi)
#pragma unroll
        for (int ni = 0; ni < 4; ++ni) acc[mi][ni] = 0.0f;

    for (int k0 = 0; k0 < K; k0 += 32) {
#pragma unroll
        for (int l = 0; l < 2; ++l) {
            int L = tid + l * 256;
            int row = L >> 2, c8 = (L & 3) * 8;
            gload16(&A[(size_t)(bm + row) * K + k0 + c8], &As[L * 8]);
            gload16(&Bt[(size_t)(bn + row) * K + k0 + c8], &Bs[L * 8]);
        }
        __syncthreads();
        short8 af[4], bf[4];
#pragma unroll
        for (int mi = 0; mi < 4; ++mi) af[mi] = *(short8*)&As[(wr + mi * 16 + lm) * 32 + lk];
#pragma unroll
        for (int ni = 0; ni < 4; ++ni) bf[ni] = *(short8*)&Bs[(wc + ni * 16 + lm) * 32 + lk];
#pragma unroll
        for (int mi = 0; mi < 4; ++mi)
#pragma unroll
            for (int ni = 0; ni < 4; ++ni)
                acc[mi][ni] = __builtin_amdgcn_mfma_f32_16x16x32_bf16(af[mi], bf[ni], acc[mi][ni], 0, 0, 0);
        __syncthreads();
    }
    const int lr = (lane >> 4) * 4;  // C/D: col=lane&15, row=(lane>>4)*4+reg
#pragma unroll
    for (int mi = 0; mi < 4; ++mi)
#pragma unroll
        for (int ni = 0; ni < 4; ++ni)
#pragma unroll
            for (int r = 0; r < 4; ++r) {
                int m = bm + wr + mi * 16 + lr + r;
                int n = bn + wc + ni * 16 + lm;
                C[(size_t)m * N + n] = acc[mi][ni][r];
            }
}

// ---------------------------------------------------------------------------
// attn = q k^T / sqrt(HD) via split-bf16 MFMA, causal mask to MASKVAL.
// Staged-LDS (proven R5/R7). Diagonal blocks skip MFMAs for fragments fully
// above the diagonal (their acc is discarded by the sk<=sq mask) — wave-
// uniform guard, bit-identical output.
// Fully-above-diagonal blocks write NOTHING (softmax skips those loads).
// ---------------------------------------------------------------------------
__global__ __launch_bounds__(256) void attn_qk_split(const unsigned short* __restrict__ qh,
                                                     const unsigned short* __restrict__ ql,
                                                     const unsigned short* __restrict__ kh,
                                                     const unsigned short* __restrict__ kl,
                                                     float* __restrict__ attn)
{
    const int bh = blockIdx.z;
    const int bm = blockIdx.y * 128, bn = blockIdx.x * 128;
    const int tid = threadIdx.x;

    if (blockIdx.x > blockIdx.y) return;  // fully above diagonal: never read
    const bool diag = (blockIdx.x == blockIdx.y);

    float* C = attn + (size_t)bh * Ss * Ss;
    const size_t hb = (size_t)bh * Ss * HDd;
    const unsigned short* Ah = qh + hb;
    const unsigned short* Al = ql + hb;
    const unsigned short* Bh = kh + hb;
    const unsigned short* Bl = kl + hb;

    __shared__ unsigned short AsH[128 * 32], AsL[128 * 32];
    __shared__ unsigned short BsH[128 * 32], BsL[128 * 32];
    const int lane = tid & 63, wid = tid >> 6;
    const int wr = (wid >> 1) * 64, wc = (wid & 1) * 64;
    const int lm = lane & 15, lk = (lane >> 4) * 8;

    f32x4 acc[4][4];
#pragma unroll
    for (int mi = 0; mi < 4; ++mi)
#pragma unroll
        for (int ni = 0; ni < 4; ++ni) acc[mi][ni] = 0.0f;

    for (int k0 = 0; k0 < HDd; k0 += 32) {
#pragma unroll
        for (int l = 0; l < 2; ++l) {
            int L = tid + l * 256;
            int row = L >> 2, c8 = (L & 3) * 8;
            size_t ga = (size_t)(bm + row) * HDd + k0 + c8;
            size_t gb = (size_t)(bn + row) * HDd + k0 + c8;
            gload16(&Ah[ga], &AsH[L * 8]);
            gload16(&Al[ga], &AsL[L * 8]);
            gload16(&Bh[gb], &BsH[L * 8]);
            gload16(&Bl[gb], &BsL[L * 8]);
        }
        __syncthreads();
        short8 ah[4], al[4], bh2[4], bl2[4];
#pragma unroll
        for (int mi = 0; mi < 4; ++mi) {
            ah[mi] = *(short8*)&AsH[(wr + mi * 16 + lm) * 32 + lk];
            al[mi] = *(short8*)&AsL[(wr + mi * 16 + lm) * 32 + lk];
        }
#pragma unroll
        for (int ni = 0; ni < 4; ++ni) {
            bh2[ni] = *(short8*)&BsH[(wc + ni * 16 + lm) * 32 + lk];
            bl2[ni] = *(short8*)&BsL[(wc + ni * 16 + lm) * 32 + lk];
        }
#pragma unroll
        for (int mi = 0; mi < 4; ++mi)
#pragma unroll
            for (int ni = 0; ni < 4; ++ni) {
                if (diag && (wc + ni * 16 > wr + mi * 16 + 15)) continue; // acc unused (masked)
                acc[mi][ni] = __builtin_amdgcn_mfma_f32_16x16x32_bf16(ah[mi], bh2[ni], acc[mi][ni], 0, 0, 0);
                acc[mi][ni] = __builtin_amdgcn_mfma_f32_16x16x32_bf16(ah[mi], bl2[ni], acc[mi][ni], 0, 0, 0);
                acc[mi][ni] = __builtin_amdgcn_mfma_f32_16x16x32_bf16(al[mi], bh2[ni], acc[mi][ni], 0, 0, 0);
            }
        __syncthreads();
    }
    const float scale = 0.08838834764831845f;  // 1/sqrt(128)
    const int lr = (lane >> 4) * 4;
#pragma unroll
    for (int mi = 0; mi < 4; ++mi)
#pragma unroll
        for (int ni = 0; ni < 4; ++ni)
#pragma unroll
            for (int r = 0; r < 4; ++r) {
                int sq = bm + wr + mi * 16 + lr + r;
                int sk = bn + wc + ni * 16 + lm;
                C[(size_t)sq * Ss + sk] = (sk <= sq) ? acc[mi][ni][r] * scale : MASKVAL;
            }
}

// ---------------------------------------------------------------------------
// Row softmax IN PLACE with causal load-skip. Inactive lanes write zeros —
// REQUIRED: the scan reads 256-col chunks that extend past the diagonal
// into blocks attn_qk skipped.
// ---------------------------------------------------------------------------
__global__ __launch_bounds__(256) void softmax_rows(float* __restrict__ attn)
{
    int row = blockIdx.x;
    int r = row & (Ss - 1);
    float4* a4 = (float4*)(attn + (size_t)row * Ss);
    int tid = threadIdx.x;
    bool act = (tid * 4 <= r);
    float4 x = make_float4(MASKVAL, MASKVAL, MASKVAL, MASKVAL);
    if (act) x = a4[tid];
    float m = fmaxf(fmaxf(x.x, x.y), fmaxf(x.z, x.w));
#pragma unroll
    for (int off = 32; off; off >>= 1) m = fmaxf(m, __shfl_xor(m, off));
    __shared__ float red[4];
    if ((tid & 63) == 0) red[tid >> 6] = m;
    __syncthreads();
    float mm = fmaxf(fmaxf(red[0], red[1]), fmaxf(red[2], red[3]));
    float e0 = expf(x.x - mm), e1 = expf(x.y - mm);
    float e2 = expf(x.z - mm), e3 = expf(x.w - mm);
    float s = e0 + e1 + e2 + e3;
#pragma unroll
    for (int off = 32; off; off >>= 1) s += __shfl_xor(s, off);
    __shared__ float red2[4];
    if ((tid & 63) == 0) red2[tid >> 6] = s;
    __syncthreads();
    float inv = 1.0f / (red2[0] + red2[1] + red2[2] + red2[3]);
    a4[tid] = make_float4(e0 * inv, e1 * inv, e2 * inv, e3 * inv);
}

// ---------------------------------------------------------------------------
// DPP cross-lane helpers (VALU-latency, no LDS pipe).
// ---------------------------------------------------------------------------
template<int CTRL>
__device__ __forceinline__ int dpp_i(int x) {
    return __builtin_amdgcn_update_dpp(0, x, CTRL, 0xF, 0xF, true);
}
__device__ __forceinline__ float wave_sum64(float x) {
    x += __int_as_float(dpp_i<0xB1>(__float_as_int(x)));
    x += __int_as_float(dpp_i<0x4E>(__float_as_int(x)));
    x += __int_as_float(dpp_i<0x141>(__float_as_int(x)));
    x += __int_as_float(dpp_i<0x140>(__float_as_int(x)));
    int xi = __float_as_int(x);
    float a = __int_as_float(__builtin_amdgcn_readlane(xi, 0));
    float b = __int_as_float(__builtin_amdgcn_readlane(xi, 16));
    float c = __int_as_float(__builtin_amdgcn_readlane(xi, 32));
    float d = __int_as_float(__builtin_amdgcn_readlane(xi, 48));
    return (a + c) + (b + d);
}

// 64-bit packed-key (value<<32 | index) helpers: lexicographic min == exact
// float-min with first-index tie-break (values are non-negative floats).
__device__ __forceinline__ unsigned long long u64min(unsigned long long a, unsigned long long b) {
    return a < b ? a : b;
}
template<int CTRL>
__device__ __forceinline__ unsigned long long dpp64(unsigned long long x) {
    int lo = (int)(unsigned)x;
    int hi = (int)(unsigned)(x >> 32);
    unsigned l2 = (unsigned)dpp_i<CTRL>(lo);
    unsigned h2 = (unsigned)dpp_i<CTRL>(hi);
    return ((unsigned long long)h2 << 32) | (unsigned long long)l2;
}
__device__ __forceinline__ unsigned long long wave_min64k(unsigned long long x) {
    x = u64min(x, dpp64<0xB1>(x));
    x = u64min(x, dpp64<0x4E>(x));
    x = u64min(x, dpp64<0x141>(x));
    x = u64min(x, dpp64<0x140>(x));
    int lo = (int)(unsigned)x;
    int hi = (int)(unsigned)(x >> 32);
    unsigned long long a = ((unsigned long long)(unsigned)__builtin_amdgcn_readlane(hi, 0)  << 32) |
                           (unsigned long long)(unsigned)__builtin_amdgcn_readlane(lo, 0);
    unsigned long long b = ((unsigned long long)(unsigned)__builtin_amdgcn_readlane(hi, 16) << 32) |
                           (unsigned long long)(unsigned)__builtin_amdgcn_readlane(lo, 16);
    unsigned long long c = ((unsigned long long)(unsigned)__builtin_amdgcn_readlane(hi, 32) << 32) |
                           (unsigned long long)(unsigned)__builtin_amdgcn_readlane(lo, 32);
    unsigned long long d = ((unsigned long long)(unsigned)__builtin_amdgcn_readlane(hi, 48) << 32) |
                           (unsigned long long)(unsigned)__builtin_amdgcn_readlane(lo, 48);
    return u64min(u64min(a, b), u64min(c, d));
}

__device__ __forceinline__ float f4c(float4 v, int i) {
    return i == 0 ? v.x : (i == 1 ? v.y : (i == 2 ? v.z : v.w));
}

// ---------------------------------------------------------------------------
// A2S sequential scan v5 (proven 390 us): single wave, branchless, causal
// chunk gating via template NC phases, float mf mask, packed u64 argmin.
// ---------------------------------------------------------------------------
template<int NC, int NCL>
__device__ __forceinline__ void scan_step(int t, int lane,
                                          const float4* __restrict__ A4,
                                          unsigned char* __restrict__ KP,
                                          float4 (&rb)[4],
                                          float (&sel)[4][4],
                                          float (&mf)[4][4])
{
    const float INFv = __int_as_float(0x7f800000);
    // snapshot row t
    float4 a[NC];
#pragma unroll
    for (int jj = 0; jj < NC; ++jj) a[jj] = rb[jj];
    // prefetch row t+4 (clamped), NCL chunks (one lookahead chunk past NC)
    int tp = t + 4; if (tp > Ss - 1) tp = Ss - 1;
#pragma unroll
    for (int jj = 0; jj < NCL; ++jj) rb[jj] = A4[tp * 256 + jj * 64 + lane];

    // masked row sum — identical add order to v4 (skipped chunks added 0.0)
    float lsum = 0.0f;
#pragma unroll
    for (int jj = 0; jj < NC; ++jj) {
        float c0 = a[jj].x * mf[jj][0], c1 = a[jj].y * mf[jj][1];
        float c2 = a[jj].z * mf[jj][2], c3 = a[jj].w * mf[jj][3];
        lsum += (c0 + c1) + (c2 + c3);
    }
    float tot = wave_sum64(lsum);
    float inv = 1.0f / tot;

    const int local = t - RBc;
    const int base = lane * 4;
    const bool ge = (base >= SBc);   // SBc%4==0 -> i-independent

    // sel update + windowed argmin via packed (value,index) keys
    unsigned long long kmin = 0xFFFFFFFFFFFFFFFFull;
#pragma unroll
    for (int jj = 0; jj < NC; ++jj) {
        unsigned long long kk[4];
#pragma unroll
        for (int i = 0; i < 4; ++i) {
            float sv = fmaf(FFf, sel[jj][i], f4c(a[jj], i) * inv);
            sel[jj][i] = sv;
            int s = jj * 256 + base + i;
            bool win = (s <= local) && (jj > 0 || ge);
            unsigned hi = win ? __float_as_uint(sv) : 0x7f800000u;
            kk[i] = ((unsigned long long)hi << 32) | (unsigned long long)(unsigned)s;
        }
        unsigned long long cm = u64min(u64min(kk[0], kk[1]), u64min(kk[2], kk[3]));
        kmin = u64min(kmin, cm);
    }
    kmin = wave_min64k(kmin);
    const int besti = (int)(unsigned)(kmin & 0xFFFFFFFFull);

    // evict + mask update
#pragma unroll
    for (int jj = 0; jj < NC; ++jj)
#pragma unroll
        for (int i = 0; i < 4; ++i) {
            int s = jj * 256 + base + i;
            bool e = (s == besti);
            sel[jj][i] = e ? INFv : sel[jj][i];
            mf[jj][i]  = e ? 0.0f : mf[jj][i];
        }

    // keep row t+1 (chunks 0..NC-1; scores are exactly 0 above, don't-care)
    uchar4* kp4 = (uchar4*)(KP + (size_t)(t + 1) * Ss);
#pragma unroll
    for (int jj = 0; jj < NC; ++jj) {
        uchar4 kb;
        kb.x = (unsigned char)mf[jj][0];
        kb.y = (unsigned char)mf[jj][1];
        kb.z = (unsigned char)mf[jj][2];
        kb.w = (unsigned char)mf[jj][3];
        kp4[jj * 64 + lane] = kb;
    }
}

__global__ __launch_bounds__(64) void scan_kernel5(const float* __restrict__ scores,
                                                   unsigned char* __restrict__ keep)
{
    int bh = blockIdx.x;
    int lane = threadIdx.x;
    const float4* A4 = (const float4*)(scores + (size_t)bh * Ss * Ss);
    unsigned char* KP = keep + (size_t)bh * Ss * Ss;

    float sel[4][4];
    float mf[4][4];
#pragma unroll
    for (int jj = 0; jj < 4; ++jj)
#pragma unroll
        for (int i = 0; i < 4; ++i) { sel[jj][i] = 0.0f; mf[jj][i] = 1.0f; }

    // ---- warmup rows 0..162: chunk 0 only (rows <163 are zero beyond col 162) ----
    float4 w0 = A4[0 * 256 + lane];
    float4 w1 = A4[1 * 256 + lane];
    float4 w2 = A4[2 * 256 + lane];
    float4 w3 = A4[3 * 256 + lane];
#define WSTEP(W, NEXT)                                                       \
    do {                                                                     \
        float4 _a = W;                                                       \
        W = A4[(NEXT) * 256 + lane];                                         \
        sel[0][0] = fmaf(FFf, sel[0][0], _a.x);                              \
        sel[0][1] = fmaf(FFf, sel[0][1], _a.y);                              \
        sel[0][2] = fmaf(FFf, sel[0][2], _a.z);                              \
        sel[0][3] = fmaf(FFf, sel[0][3], _a.w);                              \
    } while (0)
    for (int r = 0; r < 160; r += 4) {
        WSTEP(w0, r + 4); WSTEP(w1, r + 5); WSTEP(w2, r + 6); WSTEP(w3, r + 7);
    }
#undef WSTEP
    {   // rows 160..162 tail (w3 = row 163 discarded)
        float4 tl[3] = { w0, w1, w2 };
#pragma unroll
        for (int u = 0; u < 3; ++u) {
            sel[0][0] = fmaf(FFf, sel[0][0], tl[u].x);
            sel[0][1] = fmaf(FFf, sel[0][1], tl[u].y);
            sel[0][2] = fmaf(FFf, sel[0][2], tl[u].z);
            sel[0][3] = fmaf(FFf, sel[0][3], tl[u].w);
        }
    }

    // ---- init scan prefetch: rows 163..166, chunk 0 ----
    float4 rb[4][4];
#pragma unroll
    for (int slot = 0; slot < 4; ++slot)
        rb[slot][0] = A4[(163 + slot) * 256 + lane];

    // ---- phased scan: t = 163..1022 (keep rows 164..1023) ----
    for (int t0 = 163; t0 < 255; t0 += 4) {           // 92 steps, NC=1
        scan_step<1, 2>(t0 + 0, lane, A4, KP, rb[0], sel, mf);
        scan_step<1, 2>(t0 + 1, lane, A4, KP, rb[1], sel, mf);
        scan_step<1, 2>(t0 + 2, lane, A4, KP, rb[2], sel, mf);
        scan_step<1, 2>(t0 + 3, lane, A4, KP, rb[3], sel, mf);
    }
    for (int t0 = 255; t0 < 511; t0 += 4) {           // 256 steps, NC=2
        scan_step<2, 3>(t0 + 0, lane, A4, KP, rb[0], sel, mf);
        scan_step<2, 3>(t0 + 1, lane, A4, KP, rb[1], sel, mf);
        scan_step<2, 3>(t0 + 2, lane, A4, KP, rb[2], sel, mf);
        scan_step<2, 3>(t0 + 3, lane, A4, KP, rb[3], sel, mf);
    }
    for (int t0 = 511; t0 < 767; t0 += 4) {           // 256 steps, NC=3
        scan_step<3, 4>(t0 + 0, lane, A4, KP, rb[0], sel, mf);
        scan_step<3, 4>(t0 + 1, lane, A4, KP, rb[1], sel, mf);
        scan_step<3, 4>(t0 + 2, lane, A4, KP, rb[2], sel, mf);
        scan_step<3, 4>(t0 + 3, lane, A4, KP, rb[3], sel, mf);
    }
    for (int t0 = 767; t0 < 1023; t0 += 4) {          // 256 steps, NC=4
        scan_step<4, 4>(t0 + 0, lane, A4, KP, rb[0], sel, mf);
        scan_step<4, 4>(t0 + 1, lane, A4, KP, rb[1], sel, mf);
        scan_step<4, 4>(t0 + 2, lane, A4, KP, rb[2], sel, mf);
        scan_step<4, 4>(t0 + 3, lane, A4, KP, rb[3], sel, mf);
    }
}

// ---------------------------------------------------------------------------
// Fused mask + renorm + PV: ctx = (keep.*P) @ V / rowsum(keep.*P).
// v2: float4 LDS reads (As padded to [16][68], Bs rows 256B-aligned).
// ---------------------------------------------------------------------------
__global__ __launch_bounds__(256) void pv_renorm(const float* __restrict__ scores,
                                                 const unsigned char* __restrict__ keep,
                                                 const float* __restrict__ v,
                                                 unsigned short* __restrict__ ctxb)
{
    int bh = blockIdx.z;
    int b_ = bh / NHh, h_ = bh % NHh;
    const float* P = scores + (size_t)bh * Ss * Ss;
    const unsigned char* KPm = keep + (size_t)bh * Ss * Ss;
    const float* V = v + (size_t)bh * Ss * HDd;
    int bm = blockIdx.y * 64, bn = blockIdx.x * 64;
    int tid = threadIdx.x, tx = tid & 15, ty = tid >> 4;
    __shared__ float As[16][68];
    __shared__ float Bs[16][64];
    float acc[4][4] = {};
    float rs[4] = {};
    int kend = bm + 64;  // causal truncation (covers full causal row extent)
    for (int k0 = 0; k0 < kend; k0 += 16) {
#pragma unroll
        for (int l = 0; l < 4; ++l) {
            int idx = tid + l * 256;
            int r = idx >> 4, c = idx & 15;
            int row = bm + r;
            float p = P[(size_t)row * Ss + k0 + c];
            if (row > CBc && !KPm[(size_t)row * Ss + k0 + c]) p = 0.0f;
            As[c][r] = p;
        }
#pragma unroll
        for (int l = 0; l < 4; ++l) {
            int idx = tid + l * 256;
            int r = idx >> 6, c = idx & 63;
            Bs[r][c] = V[(size_t)(k0 + r) * HDd + bn + c];
        }
        __syncthreads();
#pragma unroll
        for (int kk = 0; kk < 16; ++kk) {
            float4 av = *(const float4*)&As[kk][ty * 4];
            float4 bv = *(const float4*)&Bs[kk][tx * 4];
            float a[4] = { av.x, av.y, av.z, av.w };
            float b[4] = { bv.x, bv.y, bv.z, bv.w };
#pragma unroll
            for (int i = 0; i < 4; ++i) rs[i] += a[i];
#pragma unroll
            for (int i = 0; i < 4; ++i)
#pragma unroll
                for (int j = 0; j < 4; ++j)
                    acc[i][j] = fmaf(a[i], b[j], acc[i][j]);
        }
        __syncthreads();
    }
#pragma unroll
    for (int i = 0; i < 4; ++i) {
        float inv = 1.0f / rs[i];   // rs > 0 (diagonal prob always kept)
        int sq = bm + ty * 4 + i;
#pragma unroll
        for (int j = 0; j < 4; ++j) {
            int d = bn + tx * 4 + j;
            ctxb[(size_t)(b_ * Ss + sq) * HIDd + h_ * HDd + d] = f2b(acc[i][j] * inv);
        }
    }
}

// ---------------------------------------------------------------------------
extern "C" void kernel_launch(void* const* d_in, const int* in_sizes, int n_in,
                              void* d_out, int out_size, void* d_ws, size_t ws_size,
                              hipStream_t stream)
{
    const float* hs = (const float*)d_in[0];
    const float* wq = (const float*)d_in[1];
    const float* wk = (const float*)d_in[2];
    const float* wv = (const float*)d_in[3];
    const float* wo = (const float*)d_in[4];
    float* out = (float*)d_out;

    float* ws = (float*)d_ws;
    size_t off = 0;
    float* qf   = ws + off; off += (size_t)NBH * Ss * HDd;   // 16 MB (reused: ctxb)
    float* kf   = ws + off; off += (size_t)NBH * Ss * HDd;   // 16 MB (unused now)
    float* vf   = ws + off; off += (size_t)NBH * Ss * HDd;   // 16 MB
    float* attn = ws + off; off += (size_t)NBH * Ss * Ss;    // 128 MB
    unsigned char* keep = (unsigned char*)(ws + off); off += (size_t)NBH * Ss * Ss / 4; // 32 MB
    unsigned short* wot = (unsigned short*)(ws + off); off += (size_t)HIDd * HIDd / 2;  // 8 MB

    // Transients overlaid on attn (dead before attn is written). 8 MB = 2M floats each.
    unsigned short* hsh  = (unsigned short*)(attn);
    unsigned short* hsl  = (unsigned short*)(attn + 2u * 1024 * 1024);
    unsigned short* wqth = (unsigned short*)(attn + 4u * 1024 * 1024);
    unsigned short* wqtl = (unsigned short*)(attn + 6u * 1024 * 1024);
    unsigned short* wkth = (unsigned short*)(attn + 8u * 1024 * 1024);
    unsigned short* wktl = (unsigned short*)(attn + 10u * 1024 * 1024);
    unsigned short* wvt  = (unsigned short*)(attn + 12u * 1024 * 1024);
    // q/k split bf16 overlaid on keep (keep written only by the scan, later):
    unsigned short* qh = (unsigned short*)keep;
    unsigned short* ql = (unsigned short*)(keep + 8u * 1024 * 1024);
    unsigned short* kh = (unsigned short*)(keep + 16u * 1024 * 1024);
    unsigned short* kl = (unsigned short*)(keep + 24u * 1024 * 1024);
    // ctxb overlays qf (qf no longer written at all):
    unsigned short* ctxb = (unsigned short*)qf;
    (void)kf;

    dim3 blk(256);
    const int M = Bb * Ss;  // 2048

    // hs -> split bf16
    conv_split<<<dim3((M * HIDd / 4 + 255) / 256), blk, 0, stream>>>(hs, hsh, hsl, M * HIDd / 4);

    // all 4 weight transposes in one launch
    tconv_all<<<dim3(HIDd / 64, HIDd / 64, 4), blk, 0, stream>>>(
        wq, wk, wv, wo, wqth, wqtl, wkth, wktl, wvt, wot);

    // merged q/k/v projection with fused RoPE (q/k -> split bf16 directly)
    gemm_qkv<<<dim3(48, M / 128), blk, 0, stream>>>(
        hsh, hsl, wqth, wqtl, wkth, wktl, wvt, qh, ql, kh, kl, vf);

    // QK^T (split-precision MFMA, staged LDS) + causal mask + diag frag skip
    attn_qk_split<<<dim3(Ss / 128, Ss / 128, NBH), blk, 0, stream>>>(qh, ql, kh, kl, attn);

    // attn -> normalized scores, in place (causal load-skip)
    softmax_rows<<<dim3(NROWS), blk, 0, stream>>>(attn);

    // sequential A2S scan -> keep mask (v5, proven)
    scan_kernel5<<<dim3(NBH), dim3(64), 0, stream>>>(attn, keep);

    // fused mask + renorm + PV (fp32 math, bf16 out)
    pv_renorm<<<dim3(HDd / 64, Ss / 64, NBH), blk, 0, stream>>>(attn, keep, vf, ctxb);

    // out = ctx @ wo (bf16 MFMA, fp32 out)
    gemm_bf16t<<<dim3(HIDd / 128, M / 128), blk, 0, stream>>>(ctxb, wot, out, M, HIDd, HIDd);
}

// Round 9
// 973.140 us; speedup vs baseline: 1.4741x; 1.4741x over previous
//
#include <hip/hip_runtime.h>
#include <math.h>

// Problem constants (from reference)
#define Bb    2
#define Ss    1024
#define HIDd  2048
#define NHh   16
#define HDd   128
#define SBc   20      // floor(0.02*1024+0.5)
#define SELBc 61      // floor(0.06*1024+0.5)
#define RBc   82      // floor(0.08*1024+0.5)
#define CBc   163     // SB+SELB+RB
#define FFf   0.9f
#define MASKVAL (-3.4028234663852886e38f)
#define NBH   (Bb*NHh)       // 32
#define NROWS (NBH*Ss)       // 32768

typedef __attribute__((ext_vector_type(8))) short short8;
typedef __attribute__((ext_vector_type(4))) float f32x4;

__device__ __forceinline__ unsigned short f2b(float f) {
    unsigned u = __float_as_uint(f);
    u = (u + 0x7FFFu + ((u >> 16) & 1u)) >> 16;   // RNE
    return (unsigned short)u;
}
__device__ __forceinline__ float b2f(unsigned short h) {
    return __uint_as_float((unsigned)h << 16);
}

// ---------------------------------------------------------------------------
// Async global->LDS direct DMA (16B/lane). LDS dest = wave-uniform base +
// lane*16 (hardware rule); all call sites below have tid-linear LDS layouts.
// ---------------------------------------------------------------------------
#if defined(__has_builtin)
#if __has_builtin(__builtin_amdgcn_global_load_lds)
#define USE_GLD 1
#endif
#endif

__device__ __forceinline__ void gload16(const void* g, void* l) {
#ifdef USE_GLD
    __builtin_amdgcn_global_load_lds(
        (const __attribute__((address_space(1))) void*)g,
        (__attribute__((address_space(3))) void*)l, 16, 0, 0);
#else
    *(short8*)l = *(const short8*)g;
#endif
}

// ---------------------------------------------------------------------------
// fp32 -> split bf16 (hi + lo). lo = bf16(x - fp32(hi)).
// ---------------------------------------------------------------------------
__global__ __launch_bounds__(256) void conv_split(const float* __restrict__ x,
                                                  unsigned short* __restrict__ yh,
                                                  unsigned short* __restrict__ yl, int n4)
{
    int i = blockIdx.x * 256 + threadIdx.x;
    if (i >= n4) return;
    float4 v = ((const float4*)x)[i];
    ushort4 h, l;
    h.x = f2b(v.x); l.x = f2b(v.x - b2f(h.x));
    h.y = f2b(v.y); l.y = f2b(v.y - b2f(h.y));
    h.z = f2b(v.z); l.z = f2b(v.z - b2f(h.z));
    h.w = f2b(v.w); l.w = f2b(v.w - b2f(h.w));
    ((ushort4*)yh)[i] = h;
    ((ushort4*)yl)[i] = l;
}

// ---------------------------------------------------------------------------
// Merged weight transpose/convert: z=0: wq->split, z=1: wk->split,
// z=2: wv->single, z=3: wo->single. W[k][n] fp32 -> Wt[n][k] bf16.
// ---------------------------------------------------------------------------
__global__ __launch_bounds__(256) void tconv_all(const float* __restrict__ wq,
                                                 const float* __restrict__ wk,
                                                 const float* __restrict__ wv,
                                                 const float* __restrict__ wo,
                                                 unsigned short* __restrict__ wqth,
                                                 unsigned short* __restrict__ wqtl,
                                                 unsigned short* __restrict__ wkth,
                                                 unsigned short* __restrict__ wktl,
                                                 unsigned short* __restrict__ wvt,
                                                 unsigned short* __restrict__ wot)
{
    __shared__ float T[64][65];
    const int z = blockIdx.z;
    const float* W = (z == 0) ? wq : (z == 1) ? wk : (z == 2) ? wv : wo;
    int n0 = blockIdx.x * 64, k0 = blockIdx.y * 64;
    int tid = threadIdx.x;
    int rr = tid >> 4, cc = (tid & 15) * 4;
#pragma unroll
    for (int p = 0; p < 4; ++p) {
        int r = rr + p * 16;
        float4 x = *(const float4*)&W[(size_t)(k0 + r) * HIDd + n0 + cc];
        T[r][cc] = x.x; T[r][cc + 1] = x.y; T[r][cc + 2] = x.z; T[r][cc + 3] = x.w;
    }
    __syncthreads();
    if (z < 2) {
        unsigned short* Wth = z ? wkth : wqth;
        unsigned short* Wtl = z ? wktl : wqtl;
#pragma unroll
        for (int p = 0; p < 4; ++p) {
            int rn = rr + p * 16;
            float v0 = T[cc][rn], v1 = T[cc + 1][rn], v2 = T[cc + 2][rn], v3 = T[cc + 3][rn];
            ushort4 h, l;
            h.x = f2b(v0); l.x = f2b(v0 - b2f(h.x));
            h.y = f2b(v1); l.y = f2b(v1 - b2f(h.y));
            h.z = f2b(v2); l.z = f2b(v2 - b2f(h.z));
            h.w = f2b(v3); l.w = f2b(v3 - b2f(h.w));
            *(ushort4*)&Wth[(size_t)(n0 + rn) * HIDd + k0 + cc] = h;
            *(ushort4*)&Wtl[(size_t)(n0 + rn) * HIDd + k0 + cc] = l;
        }
    } else {
        unsigned short* Wt = (z == 2) ? wvt : wot;
#pragma unroll
        for (int p = 0; p < 4; ++p) {
            int rn = rr + p * 16;
            ushort4 o;
            o.x = f2b(T[cc][rn]);     o.y = f2b(T[cc + 1][rn]);
            o.z = f2b(T[cc + 2][rn]); o.w = f2b(T[cc + 3][rn]);
            *(ushort4*)&Wt[(size_t)(n0 + rn) * HIDd + k0 + cc] = o;
        }
    }
}

// ---------------------------------------------------------------------------
// Merged q/k/v projection GEMM (R7-proven). Grid (48,16): region =
// blockIdx.x>>4 (0=q split, 1=k split, 2=v single); 768 blocks.
// fp32 outputs: 4B stores -> 64B contiguous per 16-lane group (coalesced).
// NOTE (R8 lesson): do NOT fuse ushort epilogues here — 2B stores at 16-lane
// granularity are half-sector writes -> ~56x HBM write amplification.
// ---------------------------------------------------------------------------
__global__ __launch_bounds__(256) void gemm_qkv(const unsigned short* __restrict__ hsh,
                                                const unsigned short* __restrict__ hsl,
                                                const unsigned short* __restrict__ wqth,
                                                const unsigned short* __restrict__ wqtl,
                                                const unsigned short* __restrict__ wkth,
                                                const unsigned short* __restrict__ wktl,
                                                const unsigned short* __restrict__ wvt,
                                                float* __restrict__ qf,
                                                float* __restrict__ kf,
                                                float* __restrict__ vf)
{
    __shared__ unsigned short AsH[128 * 32], AsL[128 * 32];
    __shared__ unsigned short BsH[128 * 32], BsL[128 * 32];
    const int tid = threadIdx.x;
    const int region = blockIdx.x >> 4;              // 0=q, 1=k, 2=v
    const int bn = (blockIdx.x & 15) * 128;
    const int bm = blockIdx.y * 128;
    const int K = HIDd;
    const int lane = tid & 63, wid = tid >> 6;
    const int wr = (wid >> 1) * 64, wc = (wid & 1) * 64;
    const int lm = lane & 15, lk = (lane >> 4) * 8;
    const int lr = (lane >> 4) * 4;

    f32x4 acc[4][4];
#pragma unroll
    for (int mi = 0; mi < 4; ++mi)
#pragma unroll
        for (int ni = 0; ni < 4; ++ni) acc[mi][ni] = 0.0f;

    if (region < 2) {
        const unsigned short* Bh = region ? wkth : wqth;
        const unsigned short* Bl = region ? wktl : wqtl;
        float* C = region ? kf : qf;
        for (int k0 = 0; k0 < K; k0 += 32) {
#pragma unroll
            for (int l = 0; l < 2; ++l) {
                int L = tid + l * 256;
                int row = L >> 2, c8 = (L & 3) * 8;
                size_t ga = (size_t)(bm + row) * K + k0 + c8;
                size_t gb = (size_t)(bn + row) * K + k0 + c8;
                gload16(&hsh[ga], &AsH[L * 8]);
                gload16(&hsl[ga], &AsL[L * 8]);
                gload16(&Bh[gb], &BsH[L * 8]);
                gload16(&Bl[gb], &BsL[L * 8]);
            }
            __syncthreads();
            short8 ah[4], al[4], bh[4], bl[4];
#pragma unroll
            for (int mi = 0; mi < 4; ++mi) {
                ah[mi] = *(short8*)&AsH[(wr + mi * 16 + lm) * 32 + lk];
                al[mi] = *(short8*)&AsL[(wr + mi * 16 + lm) * 32 + lk];
            }
#pragma unroll
            for (int ni = 0; ni < 4; ++ni) {
                bh[ni] = *(short8*)&BsH[(wc + ni * 16 + lm) * 32 + lk];
                bl[ni] = *(short8*)&BsL[(wc + ni * 16 + lm) * 32 + lk];
            }
#pragma unroll
            for (int mi = 0; mi < 4; ++mi)
#pragma unroll
                for (int ni = 0; ni < 4; ++ni) {
                    acc[mi][ni] = __builtin_amdgcn_mfma_f32_16x16x32_bf16(ah[mi], bh[ni], acc[mi][ni], 0, 0, 0);
                    acc[mi][ni] = __builtin_amdgcn_mfma_f32_16x16x32_bf16(ah[mi], bl[ni], acc[mi][ni], 0, 0, 0);
                    acc[mi][ni] = __builtin_amdgcn_mfma_f32_16x16x32_bf16(al[mi], bh[ni], acc[mi][ni], 0, 0, 0);
                }
            __syncthreads();
        }
#pragma unroll
        for (int mi = 0; mi < 4; ++mi)
#pragma unroll
            for (int ni = 0; ni < 4; ++ni)
#pragma unroll
                for (int r = 0; r < 4; ++r) {
                    int m = bm + wr + mi * 16 + lr + r;
                    int n = bn + wc + ni * 16 + lm;
                    int b_ = m / Ss, s_ = m % Ss;
                    int h_ = n / HDd, d_ = n % HDd;
                    C[(size_t)((b_ * NHh + h_) * Ss + s_) * HDd + d_] = acc[mi][ni][r];
                }
    } else {
        for (int k0 = 0; k0 < K; k0 += 32) {
#pragma unroll
            for (int l = 0; l < 2; ++l) {
                int L = tid + l * 256;
                int row = L >> 2, c8 = (L & 3) * 8;
                gload16(&hsh[(size_t)(bm + row) * K + k0 + c8], &AsH[L * 8]);
                gload16(&wvt[(size_t)(bn + row) * K + k0 + c8], &BsH[L * 8]);
            }
            __syncthreads();
            short8 af[4], bf[4];
#pragma unroll
            for (int mi = 0; mi < 4; ++mi) af[mi] = *(short8*)&AsH[(wr + mi * 16 + lm) * 32 + lk];
#pragma unroll
            for (int ni = 0; ni < 4; ++ni) bf[ni] = *(short8*)&BsH[(wc + ni * 16 + lm) * 32 + lk];
#pragma unroll
            for (int mi = 0; mi < 4; ++mi)
#pragma unroll
                for (int ni = 0; ni < 4; ++ni)
                    acc[mi][ni] = __builtin_amdgcn_mfma_f32_16x16x32_bf16(af[mi], bf[ni], acc[mi][ni], 0, 0, 0);
            __syncthreads();
        }
#pragma unroll
        for (int mi = 0; mi < 4; ++mi)
#pragma unroll
            for (int ni = 0; ni < 4; ++ni)
#pragma unroll
                for (int r = 0; r < 4; ++r) {
                    int m = bm + wr + mi * 16 + lr + r;
                    int n = bn + wc + ni * 16 + lm;
                    int b_ = m / Ss, s_ = m % Ss;
                    int h_ = n / HDd, d_ = n % HDd;
                    vf[(size_t)((b_ * NHh + h_) * Ss + s_) * HDd + d_] = acc[mi][ni][r];
                }
    }
}

// ---------------------------------------------------------------------------
// Single-bf16 MFMA GEMM (wo): C = A @ Bt^T, plain [m][n] output.
// ---------------------------------------------------------------------------
__global__ __launch_bounds__(256) void gemm_bf16t(const unsigned short* __restrict__ A,
                                                  const unsigned short* __restrict__ Bt,
                                                  float* __restrict__ C,
                                                  int M, int N, int K)
{
    __shared__ unsigned short As[128 * 32];
    __shared__ unsigned short Bs[128 * 32];
    const int tid = threadIdx.x;
    const int bm = blockIdx.y * 128, bn = blockIdx.x * 128;
    const int lane = tid & 63, wid = tid >> 6;
    const int wr = (wid >> 1) * 64, wc = (wid & 1) * 64;
    const int lm = lane & 15, lk = (lane >> 4) * 8;

    f32x4 acc[4][4];
#pragma unroll
    for (int mi = 0; mi < 4; ++mi)
#pragma unroll
        for (int ni = 0; ni < 4; ++ni) acc[mi][ni] = 0.0f;

    for (int k0 = 0; k0 < K; k0 += 32) {
#pragma unroll
        for (int l = 0; l < 2; ++l) {
            int L = tid + l * 256;
            int row = L >> 2, c8 = (L & 3) * 8;
            gload16(&A[(size_t)(bm + row) * K + k0 + c8], &As[L * 8]);
            gload16(&Bt[(size_t)(bn + row) * K + k0 + c8], &Bs[L * 8]);
        }
        __syncthreads();
        short8 af[4], bf[4];
#pragma unroll
        for (int mi = 0; mi < 4; ++mi) af[mi] = *(short8*)&As[(wr + mi * 16 + lm) * 32 + lk];
#pragma unroll
        for (int ni = 0; ni < 4; ++ni) bf[ni] = *(short8*)&Bs[(wc + ni * 16 + lm) * 32 + lk];
#pragma unroll
        for (int mi = 0; mi < 4; ++mi)
#pragma unroll
            for (int ni = 0; ni < 4; ++ni)
                acc[mi][ni] = __builtin_amdgcn_mfma_f32_16x16x32_bf16(af[mi], bf[ni], acc[mi][ni], 0, 0, 0);
        __syncthreads();
    }
    const int lr = (lane >> 4) * 4;  // C/D: col=lane&15, row=(lane>>4)*4+reg
#pragma unroll
    for (int mi = 0; mi < 4; ++mi)
#pragma unroll
        for (int ni = 0; ni < 4; ++ni)
#pragma unroll
            for (int r = 0; r < 4; ++r) {
                int m = bm + wr + mi * 16 + lr + r;
                int n = bn + wc + ni * 16 + lm;
                C[(size_t)m * N + n] = acc[mi][ni][r];
            }
}

// ---------------------------------------------------------------------------
// RoPE (fp32 math) -> split bf16 q,k (hi/lo). 64 contiguous lanes x 2B =
// 128B per store instruction — fully coalesced (R8 lesson).
// ---------------------------------------------------------------------------
__global__ __launch_bounds__(64) void rope_qk_split(const float* __restrict__ q,
                                                    const float* __restrict__ k,
                                                    unsigned short* __restrict__ qh,
                                                    unsigned short* __restrict__ ql,
                                                    unsigned short* __restrict__ kh,
                                                    unsigned short* __restrict__ kl)
{
    int idx = blockIdx.x;          // bh*S + s
    int s = idx % Ss;
    int d = threadIdx.x;           // 0..63
    float inv = powf(10000.0f, -2.0f * (float)d / 128.0f);
    float fr = (float)s * inv;
    float c = cosf(fr), sn = sinf(fr);
    size_t base = (size_t)idx * HDd;
    float q1 = q[base + d], q2 = q[base + d + 64];
    float k1 = k[base + d], k2 = k[base + d + 64];
    float qa = q1 * c - q2 * sn, qbv = q2 * c + q1 * sn;
    float ka = k1 * c - k2 * sn, kbv = k2 * c + k1 * sn;
    unsigned short h;
    h = f2b(qa);  qh[base + d]      = h; ql[base + d]      = f2b(qa  - b2f(h));
    h = f2b(qbv); qh[base + d + 64] = h; ql[base + d + 64] = f2b(qbv - b2f(h));
    h = f2b(ka);  kh[base + d]      = h; kl[base + d]      = f2b(ka  - b2f(h));
    h = f2b(kbv); kh[base + d + 64] = h; kl[base + d + 64] = f2b(kbv - b2f(h));
}

// ---------------------------------------------------------------------------
// attn = q k^T / sqrt(HD) via split-bf16 MFMA, causal mask to MASKVAL.
// Staged-LDS (proven R5/R7). Diagonal blocks skip MFMAs for fragments fully
// above the diagonal (their acc is discarded by the sk<=sq mask) — wave-
// uniform guard, bit-identical output.
// Fully-above-diagonal blocks write NOTHING (softmax skips those loads).
// ---------------------------------------------------------------------------
__global__ __launch_bounds__(256) void attn_qk_split(const unsigned short* __restrict__ qh,
                                                     const unsigned short* __restrict__ ql,
                                                     const unsigned short* __restrict__ kh,
                                                     const unsigned short* __restrict__ kl,
                                                     float* __restrict__ attn)
{
    const int bh = blockIdx.z;
    const int bm = blockIdx.y * 128, bn = blockIdx.x * 128;
    const int tid = threadIdx.x;

    if (blockIdx.x > blockIdx.y) return;  // fully above diagonal: never read
    const bool diag = (blockIdx.x == blockIdx.y);

    float* C = attn + (size_t)bh * Ss * Ss;
    const size_t hb = (size_t)bh * Ss * HDd;
    const unsigned short* Ah = qh + hb;
    const unsigned short* Al = ql + hb;
    const unsigned short* Bh = kh + hb;
    const unsigned short* Bl = kl + hb;

    __shared__ unsigned short AsH[128 * 32], AsL[128 * 32];
    __shared__ unsigned short BsH[128 * 32], BsL[128 * 32];
    const int lane = tid & 63, wid = tid >> 6;
    const int wr = (wid >> 1) * 64, wc = (wid & 1) * 64;
    const int lm = lane & 15, lk = (lane >> 4) * 8;

    f32x4 acc[4][4];
#pragma unroll
    for (int mi = 0; mi < 4; ++mi)
#pragma unroll
        for (int ni = 0; ni < 4; ++ni) acc[mi][ni] = 0.0f;

    for (int k0 = 0; k0 < HDd; k0 += 32) {
#pragma unroll
        for (int l = 0; l < 2; ++l) {
            int L = tid + l * 256;
            int row = L >> 2, c8 = (L & 3) * 8;
            size_t ga = (size_t)(bm + row) * HDd + k0 + c8;
            size_t gb = (size_t)(bn + row) * HDd + k0 + c8;
            gload16(&Ah[ga], &AsH[L * 8]);
            gload16(&Al[ga], &AsL[L * 8]);
            gload16(&Bh[gb], &BsH[L * 8]);
            gload16(&Bl[gb], &BsL[L * 8]);
        }
        __syncthreads();
        short8 ah[4], al[4], bh2[4], bl2[4];
#pragma unroll
        for (int mi = 0; mi < 4; ++mi) {
            ah[mi] = *(short8*)&AsH[(wr + mi * 16 + lm) * 32 + lk];
            al[mi] = *(short8*)&AsL[(wr + mi * 16 + lm) * 32 + lk];
        }
#pragma unroll
        for (int ni = 0; ni < 4; ++ni) {
            bh2[ni] = *(short8*)&BsH[(wc + ni * 16 + lm) * 32 + lk];
            bl2[ni] = *(short8*)&BsL[(wc + ni * 16 + lm) * 32 + lk];
        }
#pragma unroll
        for (int mi = 0; mi < 4; ++mi)
#pragma unroll
            for (int ni = 0; ni < 4; ++ni) {
                if (diag && (wc + ni * 16 > wr + mi * 16 + 15)) continue; // acc unused (masked)
                acc[mi][ni] = __builtin_amdgcn_mfma_f32_16x16x32_bf16(ah[mi], bh2[ni], acc[mi][ni], 0, 0, 0);
                acc[mi][ni] = __builtin_amdgcn_mfma_f32_16x16x32_bf16(ah[mi], bl2[ni], acc[mi][ni], 0, 0, 0);
                acc[mi][ni] = __builtin_amdgcn_mfma_f32_16x16x32_bf16(al[mi], bh2[ni], acc[mi][ni], 0, 0, 0);
            }
        __syncthreads();
    }
    const float scale = 0.08838834764831845f;  // 1/sqrt(128)
    const int lr = (lane >> 4) * 4;
#pragma unroll
    for (int mi = 0; mi < 4; ++mi)
#pragma unroll
        for (int ni = 0; ni < 4; ++ni)
#pragma unroll
            for (int r = 0; r < 4; ++r) {
                int sq = bm + wr + mi * 16 + lr + r;
                int sk = bn + wc + ni * 16 + lm;
                C[(size_t)sq * Ss + sk] = (sk <= sq) ? acc[mi][ni][r] * scale : MASKVAL;
            }
}

// ---------------------------------------------------------------------------
// Row softmax IN PLACE with causal load-skip. Inactive lanes write zeros —
// REQUIRED: the scan reads 256-col chunks that extend past the diagonal
// into blocks attn_qk skipped.
// ---------------------------------------------------------------------------
__global__ __launch_bounds__(256) void softmax_rows(float* __restrict__ attn)
{
    int row = blockIdx.x;
    int r = row & (Ss - 1);
    float4* a4 = (float4*)(attn + (size_t)row * Ss);
    int tid = threadIdx.x;
    bool act = (tid * 4 <= r);
    float4 x = make_float4(MASKVAL, MASKVAL, MASKVAL, MASKVAL);
    if (act) x = a4[tid];
    float m = fmaxf(fmaxf(x.x, x.y), fmaxf(x.z, x.w));
#pragma unroll
    for (int off = 32; off; off >>= 1) m = fmaxf(m, __shfl_xor(m, off));
    __shared__ float red[4];
    if ((tid & 63) == 0) red[tid >> 6] = m;
    __syncthreads();
    float mm = fmaxf(fmaxf(red[0], red[1]), fmaxf(red[2], red[3]));
    float e0 = expf(x.x - mm), e1 = expf(x.y - mm);
    float e2 = expf(x.z - mm), e3 = expf(x.w - mm);
    float s = e0 + e1 + e2 + e3;
#pragma unroll
    for (int off = 32; off; off >>= 1) s += __shfl_xor(s, off);
    __shared__ float red2[4];
    if ((tid & 63) == 0) red2[tid >> 6] = s;
    __syncthreads();
    float inv = 1.0f / (red2[0] + red2[1] + red2[2] + red2[3]);
    a4[tid] = make_float4(e0 * inv, e1 * inv, e2 * inv, e3 * inv);
}

// ---------------------------------------------------------------------------
// DPP cross-lane helpers (VALU-latency, no LDS pipe).
// ---------------------------------------------------------------------------
template<int CTRL>
__device__ __forceinline__ int dpp_i(int x) {
    return __builtin_amdgcn_update_dpp(0, x, CTRL, 0xF, 0xF, true);
}
__device__ __forceinline__ float wave_sum64(float x) {
    x += __int_as_float(dpp_i<0xB1>(__float_as_int(x)));
    x += __int_as_float(dpp_i<0x4E>(__float_as_int(x)));
    x += __int_as_float(dpp_i<0x141>(__float_as_int(x)));
    x += __int_as_float(dpp_i<0x140>(__float_as_int(x)));
    int xi = __float_as_int(x);
    float a = __int_as_float(__builtin_amdgcn_readlane(xi, 0));
    float b = __int_as_float(__builtin_amdgcn_readlane(xi, 16));
    float c = __int_as_float(__builtin_amdgcn_readlane(xi, 32));
    float d = __int_as_float(__builtin_amdgcn_readlane(xi, 48));
    return (a + c) + (b + d);
}

// 64-bit packed-key (value<<32 | index) helpers: lexicographic min == exact
// float-min with first-index tie-break (values are non-negative floats).
__device__ __forceinline__ unsigned long long u64min(unsigned long long a, unsigned long long b) {
    return a < b ? a : b;
}
template<int CTRL>
__device__ __forceinline__ unsigned long long dpp64(unsigned long long x) {
    int lo = (int)(unsigned)x;
    int hi = (int)(unsigned)(x >> 32);
    unsigned l2 = (unsigned)dpp_i<CTRL>(lo);
    unsigned h2 = (unsigned)dpp_i<CTRL>(hi);
    return ((unsigned long long)h2 << 32) | (unsigned long long)l2;
}
__device__ __forceinline__ unsigned long long wave_min64k(unsigned long long x) {
    x = u64min(x, dpp64<0xB1>(x));
    x = u64min(x, dpp64<0x4E>(x));
    x = u64min(x, dpp64<0x141>(x));
    x = u64min(x, dpp64<0x140>(x));
    int lo = (int)(unsigned)x;
    int hi = (int)(unsigned)(x >> 32);
    unsigned long long a = ((unsigned long long)(unsigned)__builtin_amdgcn_readlane(hi, 0)  << 32) |
                           (unsigned long long)(unsigned)__builtin_amdgcn_readlane(lo, 0);
    unsigned long long b = ((unsigned long long)(unsigned)__builtin_amdgcn_readlane(hi, 16) << 32) |
                           (unsigned long long)(unsigned)__builtin_amdgcn_readlane(lo, 16);
    unsigned long long c = ((unsigned long long)(unsigned)__builtin_amdgcn_readlane(hi, 32) << 32) |
                           (unsigned long long)(unsigned)__builtin_amdgcn_readlane(lo, 32);
    unsigned long long d = ((unsigned long long)(unsigned)__builtin_amdgcn_readlane(hi, 48) << 32) |
                           (unsigned long long)(unsigned)__builtin_amdgcn_readlane(lo, 48);
    return u64min(u64min(a, b), u64min(c, d));
}

__device__ __forceinline__ float f4c(float4 v, int i) {
    return i == 0 ? v.x : (i == 1 ? v.y : (i == 2 ? v.z : v.w));
}

// ---------------------------------------------------------------------------
// A2S sequential scan v5 (proven 390 us): single wave, branchless, causal
// chunk gating via template NC phases, float mf mask, packed u64 argmin.
// ---------------------------------------------------------------------------
template<int NC, int NCL>
__device__ __forceinline__ void scan_step(int t, int lane,
                                          const float4* __restrict__ A4,
                                          unsigned char* __restrict__ KP,
                                          float4 (&rb)[4],
                                          float (&sel)[4][4],
                                          float (&mf)[4][4])
{
    const float INFv = __int_as_float(0x7f800000);
    // snapshot row t
    float4 a[NC];
#pragma unroll
    for (int jj = 0; jj < NC; ++jj) a[jj] = rb[jj];
    // prefetch row t+4 (clamped), NCL chunks (one lookahead chunk past NC)
    int tp = t + 4; if (tp > Ss - 1) tp = Ss - 1;
#pragma unroll
    for (int jj = 0; jj < NCL; ++jj) rb[jj] = A4[tp * 256 + jj * 64 + lane];

    // masked row sum — identical add order to v4 (skipped chunks added 0.0)
    float lsum = 0.0f;
#pragma unroll
    for (int jj = 0; jj < NC; ++jj) {
        float c0 = a[jj].x * mf[jj][0], c1 = a[jj].y * mf[jj][1];
        float c2 = a[jj].z * mf[jj][2], c3 = a[jj].w * mf[jj][3];
        lsum += (c0 + c1) + (c2 + c3);
    }
    float tot = wave_sum64(lsum);
    float inv = 1.0f / tot;

    const int local = t - RBc;
    const int base = lane * 4;
    const bool ge = (base >= SBc);   // SBc%4==0 -> i-independent

    // sel update + windowed argmin via packed (value,index) keys
    unsigned long long kmin = 0xFFFFFFFFFFFFFFFFull;
#pragma unroll
    for (int jj = 0; jj < NC; ++jj) {
        unsigned long long kk[4];
#pragma unroll
        for (int i = 0; i < 4; ++i) {
            float sv = fmaf(FFf, sel[jj][i], f4c(a[jj], i) * inv);
            sel[jj][i] = sv;
            int s = jj * 256 + base + i;
            bool win = (s <= local) && (jj > 0 || ge);
            unsigned hi = win ? __float_as_uint(sv) : 0x7f800000u;
            kk[i] = ((unsigned long long)hi << 32) | (unsigned long long)(unsigned)s;
        }
        unsigned long long cm = u64min(u64min(kk[0], kk[1]), u64min(kk[2], kk[3]));
        kmin = u64min(kmin, cm);
    }
    kmin = wave_min64k(kmin);
    const int besti = (int)(unsigned)(kmin & 0xFFFFFFFFull);

    // evict + mask update
#pragma unroll
    for (int jj = 0; jj < NC; ++jj)
#pragma unroll
        for (int i = 0; i < 4; ++i) {
            int s = jj * 256 + base + i;
            bool e = (s == besti);
            sel[jj][i] = e ? INFv : sel[jj][i];
            mf[jj][i]  = e ? 0.0f : mf[jj][i];
        }

    // keep row t+1 (chunks 0..NC-1; scores are exactly 0 above, don't-care)
    uchar4* kp4 = (uchar4*)(KP + (size_t)(t + 1) * Ss);
#pragma unroll
    for (int jj = 0; jj < NC; ++jj) {
        uchar4 kb;
        kb.x = (unsigned char)mf[jj][0];
        kb.y = (unsigned char)mf[jj][1];
        kb.z = (unsigned char)mf[jj][2];
        kb.w = (unsigned char)mf[jj][3];
        kp4[jj * 64 + lane] = kb;
    }
}

__global__ __launch_bounds__(64) void scan_kernel5(const float* __restrict__ scores,
                                                   unsigned char* __restrict__ keep)
{
    int bh = blockIdx.x;
    int lane = threadIdx.x;
    const float4* A4 = (const float4*)(scores + (size_t)bh * Ss * Ss);
    unsigned char* KP = keep + (size_t)bh * Ss * Ss;

    float sel[4][4];
    float mf[4][4];
#pragma unroll
    for (int jj = 0; jj < 4; ++jj)
#pragma unroll
        for (int i = 0; i < 4; ++i) { sel[jj][i] = 0.0f; mf[jj][i] = 1.0f; }

    // ---- warmup rows 0..162: chunk 0 only (rows <163 are zero beyond col 162) ----
    float4 w0 = A4[0 * 256 + lane];
    float4 w1 = A4[1 * 256 + lane];
    float4 w2 = A4[2 * 256 + lane];
    float4 w3 = A4[3 * 256 + lane];
#define WSTEP(W, NEXT)                                                       \
    do {                                                                     \
        float4 _a = W;                                                       \
        W = A4[(NEXT) * 256 + lane];                                         \
        sel[0][0] = fmaf(FFf, sel[0][0], _a.x);                              \
        sel[0][1] = fmaf(FFf, sel[0][1], _a.y);                              \
        sel[0][2] = fmaf(FFf, sel[0][2], _a.z);                              \
        sel[0][3] = fmaf(FFf, sel[0][3], _a.w);                              \
    } while (0)
    for (int r = 0; r < 160; r += 4) {
        WSTEP(w0, r + 4); WSTEP(w1, r + 5); WSTEP(w2, r + 6); WSTEP(w3, r + 7);
    }
#undef WSTEP
    {   // rows 160..162 tail (w3 = row 163 discarded)
        float4 tl[3] = { w0, w1, w2 };
#pragma unroll
        for (int u = 0; u < 3; ++u) {
            sel[0][0] = fmaf(FFf, sel[0][0], tl[u].x);
            sel[0][1] = fmaf(FFf, sel[0][1], tl[u].y);
            sel[0][2] = fmaf(FFf, sel[0][2], tl[u].z);
            sel[0][3] = fmaf(FFf, sel[0][3], tl[u].w);
        }
    }

    // ---- init scan prefetch: rows 163..166, chunk 0 ----
    float4 rb[4][4];
#pragma unroll
    for (int slot = 0; slot < 4; ++slot)
        rb[slot][0] = A4[(163 + slot) * 256 + lane];

    // ---- phased scan: t = 163..1022 (keep rows 164..1023) ----
    for (int t0 = 163; t0 < 255; t0 += 4) {           // 92 steps, NC=1
        scan_step<1, 2>(t0 + 0, lane, A4, KP, rb[0], sel, mf);
        scan_step<1, 2>(t0 + 1, lane, A4, KP, rb[1], sel, mf);
        scan_step<1, 2>(t0 + 2, lane, A4, KP, rb[2], sel, mf);
        scan_step<1, 2>(t0 + 3, lane, A4, KP, rb[3], sel, mf);
    }
    for (int t0 = 255; t0 < 511; t0 += 4) {           // 256 steps, NC=2
        scan_step<2, 3>(t0 + 0, lane, A4, KP, rb[0], sel, mf);
        scan_step<2, 3>(t0 + 1, lane, A4, KP, rb[1], sel, mf);
        scan_step<2, 3>(t0 + 2, lane, A4, KP, rb[2], sel, mf);
        scan_step<2, 3>(t0 + 3, lane, A4, KP, rb[3], sel, mf);
    }
    for (int t0 = 511; t0 < 767; t0 += 4) {           // 256 steps, NC=3
        scan_step<3, 4>(t0 + 0, lane, A4, KP, rb[0], sel, mf);
        scan_step<3, 4>(t0 + 1, lane, A4, KP, rb[1], sel, mf);
        scan_step<3, 4>(t0 + 2, lane, A4, KP, rb[2], sel, mf);
        scan_step<3, 4>(t0 + 3, lane, A4, KP, rb[3], sel, mf);
    }
    for (int t0 = 767; t0 < 1023; t0 += 4) {          // 256 steps, NC=4
        scan_step<4, 4>(t0 + 0, lane, A4, KP, rb[0], sel, mf);
        scan_step<4, 4>(t0 + 1, lane, A4, KP, rb[1], sel, mf);
        scan_step<4, 4>(t0 + 2, lane, A4, KP, rb[2], sel, mf);
        scan_step<4, 4>(t0 + 3, lane, A4, KP, rb[3], sel, mf);
    }
}

// ---------------------------------------------------------------------------
// Fused mask + renorm + PV: ctx = (keep.*P) @ V / rowsum(keep.*P).
// v2: float4 LDS reads (As padded to [16][68], Bs rows 256B-aligned).
// ---------------------------------------------------------------------------
__global__ __launch_bounds__(256) void pv_renorm(const float* __restrict__ scores,
                                                 const unsigned char* __restrict__ keep,
                                                 const float* __restrict__ v,
                                                 unsigned short* __restrict__ ctxb)
{
    int bh = blockIdx.z;
    int b_ = bh / NHh, h_ = bh % NHh;
    const float* P = scores + (size_t)bh * Ss * Ss;
    const unsigned char* KPm = keep + (size_t)bh * Ss * Ss;
    const float* V = v + (size_t)bh * Ss * HDd;
    int bm = blockIdx.y * 64, bn = blockIdx.x * 64;
    int tid = threadIdx.x, tx = tid & 15, ty = tid >> 4;
    __shared__ float As[16][68];
    __shared__ float Bs[16][64];
    float acc[4][4] = {};
    float rs[4] = {};
    int kend = bm + 64;  // causal truncation (covers full causal row extent)
    for (int k0 = 0; k0 < kend; k0 += 16) {
#pragma unroll
        for (int l = 0; l < 4; ++l) {
            int idx = tid + l * 256;
            int r = idx >> 4, c = idx & 15;
            int row = bm + r;
            float p = P[(size_t)row * Ss + k0 + c];
            if (row > CBc && !KPm[(size_t)row * Ss + k0 + c]) p = 0.0f;
            As[c][r] = p;
        }
#pragma unroll
        for (int l = 0; l < 4; ++l) {
            int idx = tid + l * 256;
            int r = idx >> 6, c = idx & 63;
            Bs[r][c] = V[(size_t)(k0 + r) * HDd + bn + c];
        }
        __syncthreads();
#pragma unroll
        for (int kk = 0; kk < 16; ++kk) {
            float4 av = *(const float4*)&As[kk][ty * 4];
            float4 bv = *(const float4*)&Bs[kk][tx * 4];
            float a[4] = { av.x, av.y, av.z, av.w };
            float b[4] = { bv.x, bv.y, bv.z, bv.w };
#pragma unroll
            for (int i = 0; i < 4; ++i) rs[i] += a[i];
#pragma unroll
            for (int i = 0; i < 4; ++i)
#pragma unroll
                for (int j = 0; j < 4; ++j)
                    acc[i][j] = fmaf(a[i], b[j], acc[i][j]);
        }
        __syncthreads();
    }
#pragma unroll
    for (int i = 0; i < 4; ++i) {
        float inv = 1.0f / rs[i];   // rs > 0 (diagonal prob always kept)
        int sq = bm + ty * 4 + i;
#pragma unroll
        for (int j = 0; j < 4; ++j) {
            int d = bn + tx * 4 + j;
            ctxb[(size_t)(b_ * Ss + sq) * HIDd + h_ * HDd + d] = f2b(acc[i][j] * inv);
        }
    }
}

// ---------------------------------------------------------------------------
extern "C" void kernel_launch(void* const* d_in, const int* in_sizes, int n_in,
                              void* d_out, int out_size, void* d_ws, size_t ws_size,
                              hipStream_t stream)
{
    const float* hs = (const float*)d_in[0];
    const float* wq = (const float*)d_in[1];
    const float* wk = (const float*)d_in[2];
    const float* wv = (const float*)d_in[3];
    const float* wo = (const float*)d_in[4];
    float* out = (float*)d_out;

    float* ws = (float*)d_ws;
    size_t off = 0;
    float* qf   = ws + off; off += (size_t)NBH * Ss * HDd;   // 16 MB (reused: ctxb)
    float* kf   = ws + off; off += (size_t)NBH * Ss * HDd;   // 16 MB
    float* vf   = ws + off; off += (size_t)NBH * Ss * HDd;   // 16 MB
    float* attn = ws + off; off += (size_t)NBH * Ss * Ss;    // 128 MB
    unsigned char* keep = (unsigned char*)(ws + off); off += (size_t)NBH * Ss * Ss / 4; // 32 MB
    unsigned short* wot = (unsigned short*)(ws + off); off += (size_t)HIDd * HIDd / 2;  // 8 MB

    // Transients overlaid on attn (dead before attn is written). 8 MB = 2M floats each.
    unsigned short* hsh  = (unsigned short*)(attn);
    unsigned short* hsl  = (unsigned short*)(attn + 2u * 1024 * 1024);
    unsigned short* wqth = (unsigned short*)(attn + 4u * 1024 * 1024);
    unsigned short* wqtl = (unsigned short*)(attn + 6u * 1024 * 1024);
    unsigned short* wkth = (unsigned short*)(attn + 8u * 1024 * 1024);
    unsigned short* wktl = (unsigned short*)(attn + 10u * 1024 * 1024);
    unsigned short* wvt  = (unsigned short*)(attn + 12u * 1024 * 1024);
    // q/k split bf16 overlaid on keep (keep written only by the scan, later):
    unsigned short* qh = (unsigned short*)keep;
    unsigned short* ql = (unsigned short*)(keep + 8u * 1024 * 1024);
    unsigned short* kh = (unsigned short*)(keep + 16u * 1024 * 1024);
    unsigned short* kl = (unsigned short*)(keep + 24u * 1024 * 1024);
    // ctxb overlays qf (qf dead after rope):
    unsigned short* ctxb = (unsigned short*)qf;

    dim3 blk(256);
    const int M = Bb * Ss;  // 2048

    // hs -> split bf16
    conv_split<<<dim3((M * HIDd / 4 + 255) / 256), blk, 0, stream>>>(hs, hsh, hsl, M * HIDd / 4);

    // all 4 weight transposes in one launch
    tconv_all<<<dim3(HIDd / 64, HIDd / 64, 4), blk, 0, stream>>>(
        wq, wk, wv, wo, wqth, wqtl, wkth, wktl, wvt, wot);

    // merged q/k/v projection (768 blocks -> 3 blocks/CU)
    gemm_qkv<<<dim3(48, M / 128), blk, 0, stream>>>(
        hsh, hsl, wqth, wqtl, wkth, wktl, wvt, qf, kf, vf);

    // RoPE (fp32 math) -> split bf16 q,k (coalesced 128B ushort stores)
    rope_qk_split<<<dim3(NBH * Ss), dim3(64), 0, stream>>>(qf, kf, qh, ql, kh, kl);

    // QK^T (split-precision MFMA, staged LDS) + causal mask + diag frag skip
    attn_qk_split<<<dim3(Ss / 128, Ss / 128, NBH), blk, 0, stream>>>(qh, ql, kh, kl, attn);

    // attn -> normalized scores, in place (causal load-skip)
    softmax_rows<<<dim3(NROWS), blk, 0, stream>>>(attn);

    // sequential A2S scan -> keep mask (v5, proven)
    scan_kernel5<<<dim3(NBH), dim3(64), 0, stream>>>(attn, keep);

    // fused mask + renorm + PV (fp32 math, bf16 out)
    pv_renorm<<<dim3(HDd / 64, Ss / 64, NBH), blk, 0, stream>>>(attn, keep, vf, ctxb);

    // out = ctx @ wo (bf16 MFMA, fp32 out)
    gemm_bf16t<<<dim3(HIDd / 128, M / 128), blk, 0, stream>>>(ctxb, wot, out, M, HIDd, HIDd);
}

// Round 10
// 969.090 us; speedup vs baseline: 1.4802x; 1.0042x over previous
//
#include <hip/hip_runtime.h>
#include <math.h>

// Problem constants (from reference)
#define Bb    2
#define Ss    1024
#define HIDd  2048
#define NHh   16
#define HDd   128
#define SBc   20      // floor(0.02*1024+0.5)
#define SELBc 61      // floor(0.06*1024+0.5)
#define RBc   82      // floor(0.08*1024+0.5)
#define CBc   163     // SB+SELB+RB
#define FFf   0.9f
#define MASKVAL (-3.4028234663852886e38f)
#define NBH   (Bb*NHh)       // 32
#define NROWS (NBH*Ss)       // 32768

typedef __attribute__((ext_vector_type(8))) short short8;
typedef __attribute__((ext_vector_type(4))) float f32x4;

__device__ __forceinline__ unsigned short f2b(float f) {
    unsigned u = __float_as_uint(f);
    u = (u + 0x7FFFu + ((u >> 16) & 1u)) >> 16;   // RNE
    return (unsigned short)u;
}
__device__ __forceinline__ float b2f(unsigned short h) {
    return __uint_as_float((unsigned)h << 16);
}

// ---------------------------------------------------------------------------
// Async global->LDS direct DMA (16B/lane). LDS dest = wave-uniform base +
// lane*16 (hardware rule); all call sites below have tid-linear LDS layouts.
// ---------------------------------------------------------------------------
#if defined(__has_builtin)
#if __has_builtin(__builtin_amdgcn_global_load_lds)
#define USE_GLD 1
#endif
#endif

__device__ __forceinline__ void gload16(const void* g, void* l) {
#ifdef USE_GLD
    __builtin_amdgcn_global_load_lds(
        (const __attribute__((address_space(1))) void*)g,
        (__attribute__((address_space(3))) void*)l, 16, 0, 0);
#else
    *(short8*)l = *(const short8*)g;
#endif
}

// ---------------------------------------------------------------------------
// fp32 -> split bf16 (hi + lo). lo = bf16(x - fp32(hi)).
// ---------------------------------------------------------------------------
__global__ __launch_bounds__(256) void conv_split(const float* __restrict__ x,
                                                  unsigned short* __restrict__ yh,
                                                  unsigned short* __restrict__ yl, int n4)
{
    int i = blockIdx.x * 256 + threadIdx.x;
    if (i >= n4) return;
    float4 v = ((const float4*)x)[i];
    ushort4 h, l;
    h.x = f2b(v.x); l.x = f2b(v.x - b2f(h.x));
    h.y = f2b(v.y); l.y = f2b(v.y - b2f(h.y));
    h.z = f2b(v.z); l.z = f2b(v.z - b2f(h.z));
    h.w = f2b(v.w); l.w = f2b(v.w - b2f(h.w));
    ((ushort4*)yh)[i] = h;
    ((ushort4*)yl)[i] = l;
}

// ---------------------------------------------------------------------------
// Merged weight transpose/convert: z=0: wq->split, z=1: wk->split,
// z=2: wv->single, z=3: wo->single. W[k][n] fp32 -> Wt[n][k] bf16.
// ---------------------------------------------------------------------------
__global__ __launch_bounds__(256) void tconv_all(const float* __restrict__ wq,
                                                 const float* __restrict__ wk,
                                                 const float* __restrict__ wv,
                                                 const float* __restrict__ wo,
                                                 unsigned short* __restrict__ wqth,
                                                 unsigned short* __restrict__ wqtl,
                                                 unsigned short* __restrict__ wkth,
                                                 unsigned short* __restrict__ wktl,
                                                 unsigned short* __restrict__ wvt,
                                                 unsigned short* __restrict__ wot)
{
    __shared__ float T[64][65];
    const int z = blockIdx.z;
    const float* W = (z == 0) ? wq : (z == 1) ? wk : (z == 2) ? wv : wo;
    int n0 = blockIdx.x * 64, k0 = blockIdx.y * 64;
    int tid = threadIdx.x;
    int rr = tid >> 4, cc = (tid & 15) * 4;
#pragma unroll
    for (int p = 0; p < 4; ++p) {
        int r = rr + p * 16;
        float4 x = *(const float4*)&W[(size_t)(k0 + r) * HIDd + n0 + cc];
        T[r][cc] = x.x; T[r][cc + 1] = x.y; T[r][cc + 2] = x.z; T[r][cc + 3] = x.w;
    }
    __syncthreads();
    if (z < 2) {
        unsigned short* Wth = z ? wkth : wqth;
        unsigned short* Wtl = z ? wktl : wqtl;
#pragma unroll
        for (int p = 0; p < 4; ++p) {
            int rn = rr + p * 16;
            float v0 = T[cc][rn], v1 = T[cc + 1][rn], v2 = T[cc + 2][rn], v3 = T[cc + 3][rn];
            ushort4 h, l;
            h.x = f2b(v0); l.x = f2b(v0 - b2f(h.x));
            h.y = f2b(v1); l.y = f2b(v1 - b2f(h.y));
            h.z = f2b(v2); l.z = f2b(v2 - b2f(h.z));
            h.w = f2b(v3); l.w = f2b(v3 - b2f(h.w));
            *(ushort4*)&Wth[(size_t)(n0 + rn) * HIDd + k0 + cc] = h;
            *(ushort4*)&Wtl[(size_t)(n0 + rn) * HIDd + k0 + cc] = l;
        }
    } else {
        unsigned short* Wt = (z == 2) ? wvt : wot;
#pragma unroll
        for (int p = 0; p < 4; ++p) {
            int rn = rr + p * 16;
            ushort4 o;
            o.x = f2b(T[cc][rn]);     o.y = f2b(T[cc + 1][rn]);
            o.z = f2b(T[cc + 2][rn]); o.w = f2b(T[cc + 3][rn]);
            *(ushort4*)&Wt[(size_t)(n0 + rn) * HIDd + k0 + cc] = o;
        }
    }
}

// ---------------------------------------------------------------------------
// Merged q/k/v projection GEMM (R7-proven). Grid (48,16): region =
// blockIdx.x>>4 (0=q split, 1=k split, 2=v single); 768 blocks.
// fp32 outputs: 4B stores -> 64B contiguous per 16-lane group (coalesced).
// NOTE (R8 lesson): do NOT fuse ushort epilogues here — 2B stores at 16-lane
// granularity are half-sector writes -> ~56x HBM write amplification.
// ---------------------------------------------------------------------------
__global__ __launch_bounds__(256) void gemm_qkv(const unsigned short* __restrict__ hsh,
                                                const unsigned short* __restrict__ hsl,
                                                const unsigned short* __restrict__ wqth,
                                                const unsigned short* __restrict__ wqtl,
                                                const unsigned short* __restrict__ wkth,
                                                const unsigned short* __restrict__ wktl,
                                                const unsigned short* __restrict__ wvt,
                                                float* __restrict__ qf,
                                                float* __restrict__ kf,
                                                float* __restrict__ vf)
{
    __shared__ unsigned short AsH[128 * 32], AsL[128 * 32];
    __shared__ unsigned short BsH[128 * 32], BsL[128 * 32];
    const int tid = threadIdx.x;
    const int region = blockIdx.x >> 4;              // 0=q, 1=k, 2=v
    const int bn = (blockIdx.x & 15) * 128;
    const int bm = blockIdx.y * 128;
    const int K = HIDd;
    const int lane = tid & 63, wid = tid >> 6;
    const int wr = (wid >> 1) * 64, wc = (wid & 1) * 64;
    const int lm = lane & 15, lk = (lane >> 4) * 8;
    const int lr = (lane >> 4) * 4;

    f32x4 acc[4][4];
#pragma unroll
    for (int mi = 0; mi < 4; ++mi)
#pragma unroll
        for (int ni = 0; ni < 4; ++ni) acc[mi][ni] = 0.0f;

    if (region < 2) {
        const unsigned short* Bh = region ? wkth : wqth;
        const unsigned short* Bl = region ? wktl : wqtl;
        float* C = region ? kf : qf;
        for (int k0 = 0; k0 < K; k0 += 32) {
#pragma unroll
            for (int l = 0; l < 2; ++l) {
                int L = tid + l * 256;
                int row = L >> 2, c8 = (L & 3) * 8;
                size_t ga = (size_t)(bm + row) * K + k0 + c8;
                size_t gb = (size_t)(bn + row) * K + k0 + c8;
                gload16(&hsh[ga], &AsH[L * 8]);
                gload16(&hsl[ga], &AsL[L * 8]);
                gload16(&Bh[gb], &BsH[L * 8]);
                gload16(&Bl[gb], &BsL[L * 8]);
            }
            __syncthreads();
            short8 ah[4], al[4], bh[4], bl[4];
#pragma unroll
            for (int mi = 0; mi < 4; ++mi) {
                ah[mi] = *(short8*)&AsH[(wr + mi * 16 + lm) * 32 + lk];
                al[mi] = *(short8*)&AsL[(wr + mi * 16 + lm) * 32 + lk];
            }
#pragma unroll
            for (int ni = 0; ni < 4; ++ni) {
                bh[ni] = *(short8*)&BsH[(wc + ni * 16 + lm) * 32 + lk];
                bl[ni] = *(short8*)&BsL[(wc + ni * 16 + lm) * 32 + lk];
            }
#pragma unroll
            for (int mi = 0; mi < 4; ++mi)
#pragma unroll
                for (int ni = 0; ni < 4; ++ni) {
                    acc[mi][ni] = __builtin_amdgcn_mfma_f32_16x16x32_bf16(ah[mi], bh[ni], acc[mi][ni], 0, 0, 0);
                    acc[mi][ni] = __builtin_amdgcn_mfma_f32_16x16x32_bf16(ah[mi], bl[ni], acc[mi][ni], 0, 0, 0);
                    acc[mi][ni] = __builtin_amdgcn_mfma_f32_16x16x32_bf16(al[mi], bh[ni], acc[mi][ni], 0, 0, 0);
                }
            __syncthreads();
        }
#pragma unroll
        for (int mi = 0; mi < 4; ++mi)
#pragma unroll
            for (int ni = 0; ni < 4; ++ni)
#pragma unroll
                for (int r = 0; r < 4; ++r) {
                    int m = bm + wr + mi * 16 + lr + r;
                    int n = bn + wc + ni * 16 + lm;
                    int b_ = m / Ss, s_ = m % Ss;
                    int h_ = n / HDd, d_ = n % HDd;
                    C[(size_t)((b_ * NHh + h_) * Ss + s_) * HDd + d_] = acc[mi][ni][r];
                }
    } else {
        for (int k0 = 0; k0 < K; k0 += 32) {
#pragma unroll
            for (int l = 0; l < 2; ++l) {
                int L = tid + l * 256;
                int row = L >> 2, c8 = (L & 3) * 8;
                gload16(&hsh[(size_t)(bm + row) * K + k0 + c8], &AsH[L * 8]);
                gload16(&wvt[(size_t)(bn + row) * K + k0 + c8], &BsH[L * 8]);
            }
            __syncthreads();
            short8 af[4], bf[4];
#pragma unroll
            for (int mi = 0; mi < 4; ++mi) af[mi] = *(short8*)&AsH[(wr + mi * 16 + lm) * 32 + lk];
#pragma unroll
            for (int ni = 0; ni < 4; ++ni) bf[ni] = *(short8*)&BsH[(wc + ni * 16 + lm) * 32 + lk];
#pragma unroll
            for (int mi = 0; mi < 4; ++mi)
#pragma unroll
                for (int ni = 0; ni < 4; ++ni)
                    acc[mi][ni] = __builtin_amdgcn_mfma_f32_16x16x32_bf16(af[mi], bf[ni], acc[mi][ni], 0, 0, 0);
            __syncthreads();
        }
#pragma unroll
        for (int mi = 0; mi < 4; ++mi)
#pragma unroll
            for (int ni = 0; ni < 4; ++ni)
#pragma unroll
                for (int r = 0; r < 4; ++r) {
                    int m = bm + wr + mi * 16 + lr + r;
                    int n = bn + wc + ni * 16 + lm;
                    int b_ = m / Ss, s_ = m % Ss;
                    int h_ = n / HDd, d_ = n % HDd;
                    vf[(size_t)((b_ * NHh + h_) * Ss + s_) * HDd + d_] = acc[mi][ni][r];
                }
    }
}

// ---------------------------------------------------------------------------
// Single-bf16 MFMA GEMM (wo): C = A @ Bt^T, plain [m][n] output.
// v2: 128x64 tile (grid 32x16 = 512 blocks = 2 blocks/CU vs 1 before) —
// same K-loop order per output element -> bit-identical; A panel re-read
// across the two N-blocks is L2-resident.
// ---------------------------------------------------------------------------
__global__ __launch_bounds__(256) void gemm_bf16t(const unsigned short* __restrict__ A,
                                                  const unsigned short* __restrict__ Bt,
                                                  float* __restrict__ C,
                                                  int M, int N, int K)
{
    __shared__ unsigned short As[128 * 32];
    __shared__ unsigned short Bs[64 * 32];
    const int tid = threadIdx.x;
    const int bm = blockIdx.y * 128, bn = blockIdx.x * 64;
    const int lane = tid & 63, wid = tid >> 6;
    const int wr = (wid >> 1) * 64, wc = (wid & 1) * 32;
    const int lm = lane & 15, lk = (lane >> 4) * 8;

    f32x4 acc[4][2];
#pragma unroll
    for (int mi = 0; mi < 4; ++mi)
#pragma unroll
        for (int ni = 0; ni < 2; ++ni) acc[mi][ni] = 0.0f;

    for (int k0 = 0; k0 < K; k0 += 32) {
#pragma unroll
        for (int l = 0; l < 2; ++l) {
            int L = tid + l * 256;
            int row = L >> 2, c8 = (L & 3) * 8;
            gload16(&A[(size_t)(bm + row) * K + k0 + c8], &As[L * 8]);
        }
        {
            int row = tid >> 2, c8 = (tid & 3) * 8;
            gload16(&Bt[(size_t)(bn + row) * K + k0 + c8], &Bs[tid * 8]);
        }
        __syncthreads();
        short8 af[4], bf[2];
#pragma unroll
        for (int mi = 0; mi < 4; ++mi) af[mi] = *(short8*)&As[(wr + mi * 16 + lm) * 32 + lk];
#pragma unroll
        for (int ni = 0; ni < 2; ++ni) bf[ni] = *(short8*)&Bs[(wc + ni * 16 + lm) * 32 + lk];
#pragma unroll
        for (int mi = 0; mi < 4; ++mi)
#pragma unroll
            for (int ni = 0; ni < 2; ++ni)
                acc[mi][ni] = __builtin_amdgcn_mfma_f32_16x16x32_bf16(af[mi], bf[ni], acc[mi][ni], 0, 0, 0);
        __syncthreads();
    }
    const int lr = (lane >> 4) * 4;  // C/D: col=lane&15, row=(lane>>4)*4+reg
#pragma unroll
    for (int mi = 0; mi < 4; ++mi)
#pragma unroll
        for (int ni = 0; ni < 2; ++ni)
#pragma unroll
            for (int r = 0; r < 4; ++r) {
                int m = bm + wr + mi * 16 + lr + r;
                int n = bn + wc + ni * 16 + lm;
                C[(size_t)m * N + n] = acc[mi][ni][r];
            }
}

// ---------------------------------------------------------------------------
// RoPE (fp32 math) -> split bf16 q,k (hi/lo). 64 contiguous lanes x 2B =
// 128B per store instruction — fully coalesced (R8 lesson).
// ---------------------------------------------------------------------------
__global__ __launch_bounds__(64) void rope_qk_split(const float* __restrict__ q,
                                                    const float* __restrict__ k,
                                                    unsigned short* __restrict__ qh,
                                                    unsigned short* __restrict__ ql,
                                                    unsigned short* __restrict__ kh,
                                                    unsigned short* __restrict__ kl)
{
    int idx = blockIdx.x;          // bh*S + s
    int s = idx % Ss;
    int d = threadIdx.x;           // 0..63
    float inv = powf(10000.0f, -2.0f * (float)d / 128.0f);
    float fr = (float)s * inv;
    float c = cosf(fr), sn = sinf(fr);
    size_t base = (size_t)idx * HDd;
    float q1 = q[base + d], q2 = q[base + d + 64];
    float k1 = k[base + d], k2 = k[base + d + 64];
    float qa = q1 * c - q2 * sn, qbv = q2 * c + q1 * sn;
    float ka = k1 * c - k2 * sn, kbv = k2 * c + k1 * sn;
    unsigned short h;
    h = f2b(qa);  qh[base + d]      = h; ql[base + d]      = f2b(qa  - b2f(h));
    h = f2b(qbv); qh[base + d + 64] = h; ql[base + d + 64] = f2b(qbv - b2f(h));
    h = f2b(ka);  kh[base + d]      = h; kl[base + d]      = f2b(ka  - b2f(h));
    h = f2b(kbv); kh[base + d + 64] = h; kl[base + d + 64] = f2b(kbv - b2f(h));
}

// ---------------------------------------------------------------------------
// attn = q k^T / sqrt(HD) via split-bf16 MFMA, causal mask to MASKVAL.
// Staged-LDS (proven R5/R7). Diagonal blocks skip MFMAs for fragments fully
// above the diagonal (their acc is discarded by the sk<=sq mask) — wave-
// uniform guard, bit-identical output.
// Fully-above-diagonal blocks write NOTHING (softmax skips those loads).
// ---------------------------------------------------------------------------
__global__ __launch_bounds__(256) void attn_qk_split(const unsigned short* __restrict__ qh,
                                                     const unsigned short* __restrict__ ql,
                                                     const unsigned short* __restrict__ kh,
                                                     const unsigned short* __restrict__ kl,
                                                     float* __restrict__ attn)
{
    const int bh = blockIdx.z;
    const int bm = blockIdx.y * 128, bn = blockIdx.x * 128;
    const int tid = threadIdx.x;

    if (blockIdx.x > blockIdx.y) return;  // fully above diagonal: never read
    const bool diag = (blockIdx.x == blockIdx.y);

    float* C = attn + (size_t)bh * Ss * Ss;
    const size_t hb = (size_t)bh * Ss * HDd;
    const unsigned short* Ah = qh + hb;
    const unsigned short* Al = ql + hb;
    const unsigned short* Bh = kh + hb;
    const unsigned short* Bl = kl + hb;

    __shared__ unsigned short AsH[128 * 32], AsL[128 * 32];
    __shared__ unsigned short BsH[128 * 32], BsL[128 * 32];
    const int lane = tid & 63, wid = tid >> 6;
    const int wr = (wid >> 1) * 64, wc = (wid & 1) * 64;
    const int lm = lane & 15, lk = (lane >> 4) * 8;

    f32x4 acc[4][4];
#pragma unroll
    for (int mi = 0; mi < 4; ++mi)
#pragma unroll
        for (int ni = 0; ni < 4; ++ni) acc[mi][ni] = 0.0f;

    for (int k0 = 0; k0 < HDd; k0 += 32) {
#pragma unroll
        for (int l = 0; l < 2; ++l) {
            int L = tid + l * 256;
            int row = L >> 2, c8 = (L & 3) * 8;
            size_t ga = (size_t)(bm + row) * HDd + k0 + c8;
            size_t gb = (size_t)(bn + row) * HDd + k0 + c8;
            gload16(&Ah[ga], &AsH[L * 8]);
            gload16(&Al[ga], &AsL[L * 8]);
            gload16(&Bh[gb], &BsH[L * 8]);
            gload16(&Bl[gb], &BsL[L * 8]);
        }
        __syncthreads();
        short8 ah[4], al[4], bh2[4], bl2[4];
#pragma unroll
        for (int mi = 0; mi < 4; ++mi) {
            ah[mi] = *(short8*)&AsH[(wr + mi * 16 + lm) * 32 + lk];
            al[mi] = *(short8*)&AsL[(wr + mi * 16 + lm) * 32 + lk];
        }
#pragma unroll
        for (int ni = 0; ni < 4; ++ni) {
            bh2[ni] = *(short8*)&BsH[(wc + ni * 16 + lm) * 32 + lk];
            bl2[ni] = *(short8*)&BsL[(wc + ni * 16 + lm) * 32 + lk];
        }
#pragma unroll
        for (int mi = 0; mi < 4; ++mi)
#pragma unroll
            for (int ni = 0; ni < 4; ++ni) {
                if (diag && (wc + ni * 16 > wr + mi * 16 + 15)) continue; // acc unused (masked)
                acc[mi][ni] = __builtin_amdgcn_mfma_f32_16x16x32_bf16(ah[mi], bh2[ni], acc[mi][ni], 0, 0, 0);
                acc[mi][ni] = __builtin_amdgcn_mfma_f32_16x16x32_bf16(ah[mi], bl2[ni], acc[mi][ni], 0, 0, 0);
                acc[mi][ni] = __builtin_amdgcn_mfma_f32_16x16x32_bf16(al[mi], bh2[ni], acc[mi][ni], 0, 0, 0);
            }
        __syncthreads();
    }
    const float scale = 0.08838834764831845f;  // 1/sqrt(128)
    const int lr = (lane >> 4) * 4;
#pragma unroll
    for (int mi = 0; mi < 4; ++mi)
#pragma unroll
        for (int ni = 0; ni < 4; ++ni)
#pragma unroll
            for (int r = 0; r < 4; ++r) {
                int sq = bm + wr + mi * 16 + lr + r;
                int sk = bn + wc + ni * 16 + lm;
                C[(size_t)sq * Ss + sk] = (sk <= sq) ? acc[mi][ni][r] * scale : MASKVAL;
            }
}

// ---------------------------------------------------------------------------
// Row softmax IN PLACE with causal load-skip. Inactive lanes write zeros —
// REQUIRED: the scan reads 256-col chunks that extend past the diagonal
// into blocks attn_qk skipped.
// ---------------------------------------------------------------------------
__global__ __launch_bounds__(256) void softmax_rows(float* __restrict__ attn)
{
    int row = blockIdx.x;
    int r = row & (Ss - 1);
    float4* a4 = (float4*)(attn + (size_t)row * Ss);
    int tid = threadIdx.x;
    bool act = (tid * 4 <= r);
    float4 x = make_float4(MASKVAL, MASKVAL, MASKVAL, MASKVAL);
    if (act) x = a4[tid];
    float m = fmaxf(fmaxf(x.x, x.y), fmaxf(x.z, x.w));
#pragma unroll
    for (int off = 32; off; off >>= 1) m = fmaxf(m, __shfl_xor(m, off));
    __shared__ float red[4];
    if ((tid & 63) == 0) red[tid >> 6] = m;
    __syncthreads();
    float mm = fmaxf(fmaxf(red[0], red[1]), fmaxf(red[2], red[3]));
    float e0 = expf(x.x - mm), e1 = expf(x.y - mm);
    float e2 = expf(x.z - mm), e3 = expf(x.w - mm);
    float s = e0 + e1 + e2 + e3;
#pragma unroll
    for (int off = 32; off; off >>= 1) s += __shfl_xor(s, off);
    __shared__ float red2[4];
    if ((tid & 63) == 0) red2[tid >> 6] = s;
    __syncthreads();
    float inv = 1.0f / (red2[0] + red2[1] + red2[2] + red2[3]);
    a4[tid] = make_float4(e0 * inv, e1 * inv, e2 * inv, e3 * inv);
}

// ---------------------------------------------------------------------------
// DPP cross-lane helpers (VALU-latency, no LDS pipe).
// ---------------------------------------------------------------------------
template<int CTRL>
__device__ __forceinline__ int dpp_i(int x) {
    return __builtin_amdgcn_update_dpp(0, x, CTRL, 0xF, 0xF, true);
}
__device__ __forceinline__ float wave_sum64(float x) {
    x += __int_as_float(dpp_i<0xB1>(__float_as_int(x)));
    x += __int_as_float(dpp_i<0x4E>(__float_as_int(x)));
    x += __int_as_float(dpp_i<0x141>(__float_as_int(x)));
    x += __int_as_float(dpp_i<0x140>(__float_as_int(x)));
    int xi = __float_as_int(x);
    float a = __int_as_float(__builtin_amdgcn_readlane(xi, 0));
    float b = __int_as_float(__builtin_amdgcn_readlane(xi, 16));
    float c = __int_as_float(__builtin_amdgcn_readlane(xi, 32));
    float d = __int_as_float(__builtin_amdgcn_readlane(xi, 48));
    return (a + c) + (b + d);
}

// 64-bit packed-key (value<<32 | index) helpers: lexicographic min == exact
// float-min with first-index tie-break (values are non-negative floats).
__device__ __forceinline__ unsigned long long u64min(unsigned long long a, unsigned long long b) {
    return a < b ? a : b;
}
template<int CTRL>
__device__ __forceinline__ unsigned long long dpp64(unsigned long long x) {
    int lo = (int)(unsigned)x;
    int hi = (int)(unsigned)(x >> 32);
    unsigned l2 = (unsigned)dpp_i<CTRL>(lo);
    unsigned h2 = (unsigned)dpp_i<CTRL>(hi);
    return ((unsigned long long)h2 << 32) | (unsigned long long)l2;
}
__device__ __forceinline__ unsigned long long wave_min64k(unsigned long long x) {
    x = u64min(x, dpp64<0xB1>(x));
    x = u64min(x, dpp64<0x4E>(x));
    x = u64min(x, dpp64<0x141>(x));
    x = u64min(x, dpp64<0x140>(x));
    int lo = (int)(unsigned)x;
    int hi = (int)(unsigned)(x >> 32);
    unsigned long long a = ((unsigned long long)(unsigned)__builtin_amdgcn_readlane(hi, 0)  << 32) |
                           (unsigned long long)(unsigned)__builtin_amdgcn_readlane(lo, 0);
    unsigned long long b = ((unsigned long long)(unsigned)__builtin_amdgcn_readlane(hi, 16) << 32) |
                           (unsigned long long)(unsigned)__builtin_amdgcn_readlane(lo, 16);
    unsigned long long c = ((unsigned long long)(unsigned)__builtin_amdgcn_readlane(hi, 32) << 32) |
                           (unsigned long long)(unsigned)__builtin_amdgcn_readlane(lo, 32);
    unsigned long long d = ((unsigned long long)(unsigned)__builtin_amdgcn_readlane(hi, 48) << 32) |
                           (unsigned long long)(unsigned)__builtin_amdgcn_readlane(lo, 48);
    return u64min(u64min(a, b), u64min(c, d));
}

__device__ __forceinline__ float f4c(float4 v, int i) {
    return i == 0 ? v.x : (i == 1 ? v.y : (i == 2 ? v.z : v.w));
}

// ---------------------------------------------------------------------------
// A2S sequential scan v5 (proven 390 us): single wave, branchless, causal
// chunk gating via template NC phases, float mf mask, packed u64 argmin.
// ---------------------------------------------------------------------------
template<int NC, int NCL>
__device__ __forceinline__ void scan_step(int t, int lane,
                                          const float4* __restrict__ A4,
                                          unsigned char* __restrict__ KP,
                                          float4 (&rb)[4],
                                          float (&sel)[4][4],
                                          float (&mf)[4][4])
{
    const float INFv = __int_as_float(0x7f800000);
    // snapshot row t
    float4 a[NC];
#pragma unroll
    for (int jj = 0; jj < NC; ++jj) a[jj] = rb[jj];
    // prefetch row t+4 (clamped), NCL chunks (one lookahead chunk past NC)
    int tp = t + 4; if (tp > Ss - 1) tp = Ss - 1;
#pragma unroll
    for (int jj = 0; jj < NCL; ++jj) rb[jj] = A4[tp * 256 + jj * 64 + lane];

    // masked row sum — identical add order to v4 (skipped chunks added 0.0)
    float lsum = 0.0f;
#pragma unroll
    for (int jj = 0; jj < NC; ++jj) {
        float c0 = a[jj].x * mf[jj][0], c1 = a[jj].y * mf[jj][1];
        float c2 = a[jj].z * mf[jj][2], c3 = a[jj].w * mf[jj][3];
        lsum += (c0 + c1) + (c2 + c3);
    }
    float tot = wave_sum64(lsum);
    float inv = 1.0f / tot;

    const int local = t - RBc;
    const int base = lane * 4;
    const bool ge = (base >= SBc);   // SBc%4==0 -> i-independent

    // sel update + windowed argmin via packed (value,index) keys
    unsigned long long kmin = 0xFFFFFFFFFFFFFFFFull;
#pragma unroll
    for (int jj = 0; jj < NC; ++jj) {
        unsigned long long kk[4];
#pragma unroll
        for (int i = 0; i < 4; ++i) {
            float sv = fmaf(FFf, sel[jj][i], f4c(a[jj], i) * inv);
            sel[jj][i] = sv;
            int s = jj * 256 + base + i;
            bool win = (s <= local) && (jj > 0 || ge);
            unsigned hi = win ? __float_as_uint(sv) : 0x7f800000u;
            kk[i] = ((unsigned long long)hi << 32) | (unsigned long long)(unsigned)s;
        }
        unsigned long long cm = u64min(u64min(kk[0], kk[1]), u64min(kk[2], kk[3]));
        kmin = u64min(kmin, cm);
    }
    kmin = wave_min64k(kmin);
    const int besti = (int)(unsigned)(kmin & 0xFFFFFFFFull);

    // evict + mask update
#pragma unroll
    for (int jj = 0; jj < NC; ++jj)
#pragma unroll
        for (int i = 0; i < 4; ++i) {
            int s = jj * 256 + base + i;
            bool e = (s == besti);
            sel[jj][i] = e ? INFv : sel[jj][i];
            mf[jj][i]  = e ? 0.0f : mf[jj][i];
        }

    // keep row t+1 (chunks 0..NC-1; scores are exactly 0 above, don't-care)
    uchar4* kp4 = (uchar4*)(KP + (size_t)(t + 1) * Ss);
#pragma unroll
    for (int jj = 0; jj < NC; ++jj) {
        uchar4 kb;
        kb.x = (unsigned char)mf[jj][0];
        kb.y = (unsigned char)mf[jj][1];
        kb.z = (unsigned char)mf[jj][2];
        kb.w = (unsigned char)mf[jj][3];
        kp4[jj * 64 + lane] = kb;
    }
}

__global__ __launch_bounds__(64) void scan_kernel5(const float* __restrict__ scores,
                                                   unsigned char* __restrict__ keep)
{
    int bh = blockIdx.x;
    int lane = threadIdx.x;
    const float4* A4 = (const float4*)(scores + (size_t)bh * Ss * Ss);
    unsigned char* KP = keep + (size_t)bh * Ss * Ss;

    float sel[4][4];
    float mf[4][4];
#pragma unroll
    for (int jj = 0; jj < 4; ++jj)
#pragma unroll
        for (int i = 0; i < 4; ++i) { sel[jj][i] = 0.0f; mf[jj][i] = 1.0f; }

    // ---- warmup rows 0..162: chunk 0 only (rows <163 are zero beyond col 162) ----
    float4 w0 = A4[0 * 256 + lane];
    float4 w1 = A4[1 * 256 + lane];
    float4 w2 = A4[2 * 256 + lane];
    float4 w3 = A4[3 * 256 + lane];
#define WSTEP(W, NEXT)                                                       \
    do {                                                                     \
        float4 _a = W;                                                       \
        W = A4[(NEXT) * 256 + lane];                                         \
        sel[0][0] = fmaf(FFf, sel[0][0], _a.x);                              \
        sel[0][1] = fmaf(FFf, sel[0][1], _a.y);                              \
        sel[0][2] = fmaf(FFf, sel[0][2], _a.z);                              \
        sel[0][3] = fmaf(FFf, sel[0][3], _a.w);                              \
    } while (0)
    for (int r = 0; r < 160; r += 4) {
        WSTEP(w0, r + 4); WSTEP(w1, r + 5); WSTEP(w2, r + 6); WSTEP(w3, r + 7);
    }
#undef WSTEP
    {   // rows 160..162 tail (w3 = row 163 discarded)
        float4 tl[3] = { w0, w1, w2 };
#pragma unroll
        for (int u = 0; u < 3; ++u) {
            sel[0][0] = fmaf(FFf, sel[0][0], tl[u].x);
            sel[0][1] = fmaf(FFf, sel[0][1], tl[u].y);
            sel[0][2] = fmaf(FFf, sel[0][2], tl[u].z);
            sel[0][3] = fmaf(FFf, sel[0][3], tl[u].w);
        }
    }

    // ---- init scan prefetch: rows 163..166, chunk 0 ----
    float4 rb[4][4];
#pragma unroll
    for (int slot = 0; slot < 4; ++slot)
        rb[slot][0] = A4[(163 + slot) * 256 + lane];

    // ---- phased scan: t = 163..1022 (keep rows 164..1023) ----
    for (int t0 = 163; t0 < 255; t0 += 4) {           // 92 steps, NC=1
        scan_step<1, 2>(t0 + 0, lane, A4, KP, rb[0], sel, mf);
        scan_step<1, 2>(t0 + 1, lane, A4, KP, rb[1], sel, mf);
        scan_step<1, 2>(t0 + 2, lane, A4, KP, rb[2], sel, mf);
        scan_step<1, 2>(t0 + 3, lane, A4, KP, rb[3], sel, mf);
    }
    for (int t0 = 255; t0 < 511; t0 += 4) {           // 256 steps, NC=2
        scan_step<2, 3>(t0 + 0, lane, A4, KP, rb[0], sel, mf);
        scan_step<2, 3>(t0 + 1, lane, A4, KP, rb[1], sel, mf);
        scan_step<2, 3>(t0 + 2, lane, A4, KP, rb[2], sel, mf);
        scan_step<2, 3>(t0 + 3, lane, A4, KP, rb[3], sel, mf);
    }
    for (int t0 = 511; t0 < 767; t0 += 4) {           // 256 steps, NC=3
        scan_step<3, 4>(t0 + 0, lane, A4, KP, rb[0], sel, mf);
        scan_step<3, 4>(t0 + 1, lane, A4, KP, rb[1], sel, mf);
        scan_step<3, 4>(t0 + 2, lane, A4, KP, rb[2], sel, mf);
        scan_step<3, 4>(t0 + 3, lane, A4, KP, rb[3], sel, mf);
    }
    for (int t0 = 767; t0 < 1023; t0 += 4) {          // 256 steps, NC=4
        scan_step<4, 4>(t0 + 0, lane, A4, KP, rb[0], sel, mf);
        scan_step<4, 4>(t0 + 1, lane, A4, KP, rb[1], sel, mf);
        scan_step<4, 4>(t0 + 2, lane, A4, KP, rb[2], sel, mf);
        scan_step<4, 4>(t0 + 3, lane, A4, KP, rb[3], sel, mf);
    }
}

// ---------------------------------------------------------------------------
// Fused mask + renorm + PV: ctx = (keep.*P) @ V / rowsum(keep.*P).
// v2: float4 LDS reads (As padded to [16][68], Bs rows 256B-aligned).
// ---------------------------------------------------------------------------
__global__ __launch_bounds__(256) void pv_renorm(const float* __restrict__ scores,
                                                 const unsigned char* __restrict__ keep,
                                                 const float* __restrict__ v,
                                                 unsigned short* __restrict__ ctxb)
{
    int bh = blockIdx.z;
    int b_ = bh / NHh, h_ = bh % NHh;
    const float* P = scores + (size_t)bh * Ss * Ss;
    const unsigned char* KPm = keep + (size_t)bh * Ss * Ss;
    const float* V = v + (size_t)bh * Ss * HDd;
    int bm = blockIdx.y * 64, bn = blockIdx.x * 64;
    int tid = threadIdx.x, tx = tid & 15, ty = tid >> 4;
    __shared__ float As[16][68];
    __shared__ float Bs[16][64];
    float acc[4][4] = {};
    float rs[4] = {};
    int kend = bm + 64;  // causal truncation (covers full causal row extent)
    for (int k0 = 0; k0 < kend; k0 += 16) {
#pragma unroll
        for (int l = 0; l < 4; ++l) {
            int idx = tid + l * 256;
            int r = idx >> 4, c = idx & 15;
            int row = bm + r;
            float p = P[(size_t)row * Ss + k0 + c];
            if (row > CBc && !KPm[(size_t)row * Ss + k0 + c]) p = 0.0f;
            As[c][r] = p;
        }
#pragma unroll
        for (int l = 0; l < 4; ++l) {
            int idx = tid + l * 256;
            int r = idx >> 6, c = idx & 63;
            Bs[r][c] = V[(size_t)(k0 + r) * HDd + bn + c];
        }
        __syncthreads();
#pragma unroll
        for (int kk = 0; kk < 16; ++kk) {
            float4 av = *(const float4*)&As[kk][ty * 4];
            float4 bv = *(const float4*)&Bs[kk][tx * 4];
            float a[4] = { av.x, av.y, av.z, av.w };
            float b[4] = { bv.x, bv.y, bv.z, bv.w };
#pragma unroll
            for (int i = 0; i < 4; ++i) rs[i] += a[i];
#pragma unroll
            for (int i = 0; i < 4; ++i)
#pragma unroll
                for (int j = 0; j < 4; ++j)
                    acc[i][j] = fmaf(a[i], b[j], acc[i][j]);
        }
        __syncthreads();
    }
#pragma unroll
    for (int i = 0; i < 4; ++i) {
        float inv = 1.0f / rs[i];   // rs > 0 (diagonal prob always kept)
        int sq = bm + ty * 4 + i;
#pragma unroll
        for (int j = 0; j < 4; ++j) {
            int d = bn + tx * 4 + j;
            ctxb[(size_t)(b_ * Ss + sq) * HIDd + h_ * HDd + d] = f2b(acc[i][j] * inv);
        }
    }
}

// ---------------------------------------------------------------------------
extern "C" void kernel_launch(void* const* d_in, const int* in_sizes, int n_in,
                              void* d_out, int out_size, void* d_ws, size_t ws_size,
                              hipStream_t stream)
{
    const float* hs = (const float*)d_in[0];
    const float* wq = (const float*)d_in[1];
    const float* wk = (const float*)d_in[2];
    const float* wv = (const float*)d_in[3];
    const float* wo = (const float*)d_in[4];
    float* out = (float*)d_out;

    float* ws = (float*)d_ws;
    size_t off = 0;
    float* qf   = ws + off; off += (size_t)NBH * Ss * HDd;   // 16 MB (reused: ctxb)
    float* kf   = ws + off; off += (size_t)NBH * Ss * HDd;   // 16 MB
    float* vf   = ws + off; off += (size_t)NBH * Ss * HDd;   // 16 MB
    float* attn = ws + off; off += (size_t)NBH * Ss * Ss;    // 128 MB
    unsigned char* keep = (unsigned char*)(ws + off); off += (size_t)NBH * Ss * Ss / 4; // 32 MB
    unsigned short* wot = (unsigned short*)(ws + off); off += (size_t)HIDd * HIDd / 2;  // 8 MB

    // Transients overlaid on attn (dead before attn is written). 8 MB = 2M floats each.
    unsigned short* hsh  = (unsigned short*)(attn);
    unsigned short* hsl  = (unsigned short*)(attn + 2u * 1024 * 1024);
    unsigned short* wqth = (unsigned short*)(attn + 4u * 1024 * 1024);
    unsigned short* wqtl = (unsigned short*)(attn + 6u * 1024 * 1024);
    unsigned short* wkth = (unsigned short*)(attn + 8u * 1024 * 1024);
    unsigned short* wktl = (unsigned short*)(attn + 10u * 1024 * 1024);
    unsigned short* wvt  = (unsigned short*)(attn + 12u * 1024 * 1024);
    // q/k split bf16 overlaid on keep (keep written only by the scan, later):
    unsigned short* qh = (unsigned short*)keep;
    unsigned short* ql = (unsigned short*)(keep + 8u * 1024 * 1024);
    unsigned short* kh = (unsigned short*)(keep + 16u * 1024 * 1024);
    unsigned short* kl = (unsigned short*)(keep + 24u * 1024 * 1024);
    // ctxb overlays qf (qf dead after rope):
    unsigned short* ctxb = (unsigned short*)qf;

    dim3 blk(256);
    const int M = Bb * Ss;  // 2048

    // hs -> split bf16
    conv_split<<<dim3((M * HIDd / 4 + 255) / 256), blk, 0, stream>>>(hs, hsh, hsl, M * HIDd / 4);

    // all 4 weight transposes in one launch
    tconv_all<<<dim3(HIDd / 64, HIDd / 64, 4), blk, 0, stream>>>(
        wq, wk, wv, wo, wqth, wqtl, wkth, wktl, wvt, wot);

    // merged q/k/v projection (768 blocks -> 3 blocks/CU)
    gemm_qkv<<<dim3(48, M / 128), blk, 0, stream>>>(
        hsh, hsl, wqth, wqtl, wkth, wktl, wvt, qf, kf, vf);

    // RoPE (fp32 math) -> split bf16 q,k (coalesced 128B ushort stores)
    rope_qk_split<<<dim3(NBH * Ss), dim3(64), 0, stream>>>(qf, kf, qh, ql, kh, kl);

    // QK^T (split-precision MFMA, staged LDS) + causal mask + diag frag skip
    attn_qk_split<<<dim3(Ss / 128, Ss / 128, NBH), blk, 0, stream>>>(qh, ql, kh, kl, attn);

    // attn -> normalized scores, in place (causal load-skip)
    softmax_rows<<<dim3(NROWS), blk, 0, stream>>>(attn);

    // sequential A2S scan -> keep mask (v5, proven)
    scan_kernel5<<<dim3(NBH), dim3(64), 0, stream>>>(attn, keep);

    // fused mask + renorm + PV (fp32 math, bf16 out)
    pv_renorm<<<dim3(HDd / 64, Ss / 64, NBH), blk, 0, stream>>>(attn, keep, vf, ctxb);

    // out = ctx @ wo (bf16 MFMA, fp32 out) — 128x64 tile, 2 blocks/CU
    gemm_bf16t<<<dim3(HIDd / 64, M / 128), blk, 0, stream>>>(ctxb, wot, out, M, HIDd, HIDd);
}

// Round 11
// 903.765 us; speedup vs baseline: 1.5872x; 1.0723x over previous
//
#include <hip/hip_runtime.h>
#include <math.h>

// Problem constants (from reference)
#define Bb    2
#define Ss    1024
#define HIDd  2048
#define NHh   16
#define HDd   128
#define SBc   20      // floor(0.02*1024+0.5)
#define SELBc 61      // floor(0.06*1024+0.5)
#define RBc   82      // floor(0.08*1024+0.5)
#define CBc   163     // SB+SELB+RB
#define FFf   0.9f
#define MASKVAL (-3.4028234663852886e38f)
#define NBH   (Bb*NHh)       // 32
#define NROWS (NBH*Ss)       // 32768

typedef __attribute__((ext_vector_type(8))) short short8;
typedef __attribute__((ext_vector_type(4))) float f32x4;

__device__ __forceinline__ unsigned short f2b(float f) {
    unsigned u = __float_as_uint(f);
    u = (u + 0x7FFFu + ((u >> 16) & 1u)) >> 16;   // RNE
    return (unsigned short)u;
}
__device__ __forceinline__ float b2f(unsigned short h) {
    return __uint_as_float((unsigned)h << 16);
}

// ---------------------------------------------------------------------------
// Async global->LDS direct DMA (16B/lane). LDS dest = wave-uniform base +
// lane*16 (hardware rule); all call sites below have tid-linear LDS layouts.
// ---------------------------------------------------------------------------
#if defined(__has_builtin)
#if __has_builtin(__builtin_amdgcn_global_load_lds)
#define USE_GLD 1
#endif
#endif

__device__ __forceinline__ void gload16(const void* g, void* l) {
#ifdef USE_GLD
    __builtin_amdgcn_global_load_lds(
        (const __attribute__((address_space(1))) void*)g,
        (__attribute__((address_space(3))) void*)l, 16, 0, 0);
#else
    *(short8*)l = *(const short8*)g;
#endif
}

// ---------------------------------------------------------------------------
// fp32 -> split bf16 (hi + lo). lo = bf16(x - fp32(hi)).
// ---------------------------------------------------------------------------
__global__ __launch_bounds__(256) void conv_split(const float* __restrict__ x,
                                                  unsigned short* __restrict__ yh,
                                                  unsigned short* __restrict__ yl, int n4)
{
    int i = blockIdx.x * 256 + threadIdx.x;
    if (i >= n4) return;
    float4 v = ((const float4*)x)[i];
    ushort4 h, l;
    h.x = f2b(v.x); l.x = f2b(v.x - b2f(h.x));
    h.y = f2b(v.y); l.y = f2b(v.y - b2f(h.y));
    h.z = f2b(v.z); l.z = f2b(v.z - b2f(h.z));
    h.w = f2b(v.w); l.w = f2b(v.w - b2f(h.w));
    ((ushort4*)yh)[i] = h;
    ((ushort4*)yl)[i] = l;
}

// ---------------------------------------------------------------------------
// Merged weight transpose/convert: z=0: wq->split, z=1: wk->split,
// z=2: wv->single, z=3: wo->single. W[k][n] fp32 -> Wt[n][k] bf16.
// ---------------------------------------------------------------------------
__global__ __launch_bounds__(256) void tconv_all(const float* __restrict__ wq,
                                                 const float* __restrict__ wk,
                                                 const float* __restrict__ wv,
                                                 const float* __restrict__ wo,
                                                 unsigned short* __restrict__ wqth,
                                                 unsigned short* __restrict__ wqtl,
                                                 unsigned short* __restrict__ wkth,
                                                 unsigned short* __restrict__ wktl,
                                                 unsigned short* __restrict__ wvt,
                                                 unsigned short* __restrict__ wot)
{
    __shared__ float T[64][65];
    const int z = blockIdx.z;
    const float* W = (z == 0) ? wq : (z == 1) ? wk : (z == 2) ? wv : wo;
    int n0 = blockIdx.x * 64, k0 = blockIdx.y * 64;
    int tid = threadIdx.x;
    int rr = tid >> 4, cc = (tid & 15) * 4;
#pragma unroll
    for (int p = 0; p < 4; ++p) {
        int r = rr + p * 16;
        float4 x = *(const float4*)&W[(size_t)(k0 + r) * HIDd + n0 + cc];
        T[r][cc] = x.x; T[r][cc + 1] = x.y; T[r][cc + 2] = x.z; T[r][cc + 3] = x.w;
    }
    __syncthreads();
    if (z < 2) {
        unsigned short* Wth = z ? wkth : wqth;
        unsigned short* Wtl = z ? wktl : wqtl;
#pragma unroll
        for (int p = 0; p < 4; ++p) {
            int rn = rr + p * 16;
            float v0 = T[cc][rn], v1 = T[cc + 1][rn], v2 = T[cc + 2][rn], v3 = T[cc + 3][rn];
            ushort4 h, l;
            h.x = f2b(v0); l.x = f2b(v0 - b2f(h.x));
            h.y = f2b(v1); l.y = f2b(v1 - b2f(h.y));
            h.z = f2b(v2); l.z = f2b(v2 - b2f(h.z));
            h.w = f2b(v3); l.w = f2b(v3 - b2f(h.w));
            *(ushort4*)&Wth[(size_t)(n0 + rn) * HIDd + k0 + cc] = h;
            *(ushort4*)&Wtl[(size_t)(n0 + rn) * HIDd + k0 + cc] = l;
        }
    } else {
        unsigned short* Wt = (z == 2) ? wvt : wot;
#pragma unroll
        for (int p = 0; p < 4; ++p) {
            int rn = rr + p * 16;
            ushort4 o;
            o.x = f2b(T[cc][rn]);     o.y = f2b(T[cc + 1][rn]);
            o.z = f2b(T[cc + 2][rn]); o.w = f2b(T[cc + 3][rn]);
            *(ushort4*)&Wt[(size_t)(n0 + rn) * HIDd + k0 + cc] = o;
        }
    }
}

// ---------------------------------------------------------------------------
// Per-head V transpose + split convert: vf[bh][s][d] fp32 -> vth/vtl[bh][d][s]
// bf16 hi/lo. tconv_split pattern (coalesced ushort4 stores).
// ---------------------------------------------------------------------------
__global__ __launch_bounds__(256) void vtrans(const float* __restrict__ vf,
                                              unsigned short* __restrict__ vth,
                                              unsigned short* __restrict__ vtl)
{
    __shared__ float T[64][65];
    const int bh = blockIdx.z;
    int d0 = blockIdx.x * 64, s0 = blockIdx.y * 64;
    int tid = threadIdx.x;
    int rr = tid >> 4, cc = (tid & 15) * 4;
    const float* V = vf + (size_t)bh * Ss * HDd;
#pragma unroll
    for (int p = 0; p < 4; ++p) {
        int r = rr + p * 16;   // s-local
        float4 x = *(const float4*)&V[(size_t)(s0 + r) * HDd + d0 + cc];
        T[r][cc] = x.x; T[r][cc + 1] = x.y; T[r][cc + 2] = x.z; T[r][cc + 3] = x.w;
    }
    __syncthreads();
#pragma unroll
    for (int p = 0; p < 4; ++p) {
        int rn = rr + p * 16;  // d-local
        float v0 = T[cc][rn], v1 = T[cc + 1][rn], v2 = T[cc + 2][rn], v3 = T[cc + 3][rn];
        ushort4 h, l;
        h.x = f2b(v0); l.x = f2b(v0 - b2f(h.x));
        h.y = f2b(v1); l.y = f2b(v1 - b2f(h.y));
        h.z = f2b(v2); l.z = f2b(v2 - b2f(h.z));
        h.w = f2b(v3); l.w = f2b(v3 - b2f(h.w));
        size_t ob = ((size_t)bh * HDd + d0 + rn) * Ss + s0 + cc;
        *(ushort4*)&vth[ob] = h;
        *(ushort4*)&vtl[ob] = l;
    }
}

// ---------------------------------------------------------------------------
// Merged q/k/v projection GEMM (R7-proven). Grid (48,16): region =
// blockIdx.x>>4 (0=q split, 1=k split, 2=v single); 768 blocks.
// NOTE (R8 lesson): do NOT fuse ushort epilogues here — 2B stores at 16-lane
// granularity are half-sector writes -> ~56x HBM write amplification.
// ---------------------------------------------------------------------------
__global__ __launch_bounds__(256) void gemm_qkv(const unsigned short* __restrict__ hsh,
                                                const unsigned short* __restrict__ hsl,
                                                const unsigned short* __restrict__ wqth,
                                                const unsigned short* __restrict__ wqtl,
                                                const unsigned short* __restrict__ wkth,
                                                const unsigned short* __restrict__ wktl,
                                                const unsigned short* __restrict__ wvt,
                                                float* __restrict__ qf,
                                                float* __restrict__ kf,
                                                float* __restrict__ vf)
{
    __shared__ unsigned short AsH[128 * 32], AsL[128 * 32];
    __shared__ unsigned short BsH[128 * 32], BsL[128 * 32];
    const int tid = threadIdx.x;
    const int region = blockIdx.x >> 4;              // 0=q, 1=k, 2=v
    const int bn = (blockIdx.x & 15) * 128;
    const int bm = blockIdx.y * 128;
    const int K = HIDd;
    const int lane = tid & 63, wid = tid >> 6;
    const int wr = (wid >> 1) * 64, wc = (wid & 1) * 64;
    const int lm = lane & 15, lk = (lane >> 4) * 8;
    const int lr = (lane >> 4) * 4;

    f32x4 acc[4][4];
#pragma unroll
    for (int mi = 0; mi < 4; ++mi)
#pragma unroll
        for (int ni = 0; ni < 4; ++ni) acc[mi][ni] = 0.0f;

    if (region < 2) {
        const unsigned short* Bh = region ? wkth : wqth;
        const unsigned short* Bl = region ? wktl : wqtl;
        float* C = region ? kf : qf;
        for (int k0 = 0; k0 < K; k0 += 32) {
#pragma unroll
            for (int l = 0; l < 2; ++l) {
                int L = tid + l * 256;
                int row = L >> 2, c8 = (L & 3) * 8;
                size_t ga = (size_t)(bm + row) * K + k0 + c8;
                size_t gb = (size_t)(bn + row) * K + k0 + c8;
                gload16(&hsh[ga], &AsH[L * 8]);
                gload16(&hsl[ga], &AsL[L * 8]);
                gload16(&Bh[gb], &BsH[L * 8]);
                gload16(&Bl[gb], &BsL[L * 8]);
            }
            __syncthreads();
            short8 ah[4], al[4], bh[4], bl[4];
#pragma unroll
            for (int mi = 0; mi < 4; ++mi) {
                ah[mi] = *(short8*)&AsH[(wr + mi * 16 + lm) * 32 + lk];
                al[mi] = *(short8*)&AsL[(wr + mi * 16 + lm) * 32 + lk];
            }
#pragma unroll
            for (int ni = 0; ni < 4; ++ni) {
                bh[ni] = *(short8*)&BsH[(wc + ni * 16 + lm) * 32 + lk];
                bl[ni] = *(short8*)&BsL[(wc + ni * 16 + lm) * 32 + lk];
            }
#pragma unroll
            for (int mi = 0; mi < 4; ++mi)
#pragma unroll
                for (int ni = 0; ni < 4; ++ni) {
                    acc[mi][ni] = __builtin_amdgcn_mfma_f32_16x16x32_bf16(ah[mi], bh[ni], acc[mi][ni], 0, 0, 0);
                    acc[mi][ni] = __builtin_amdgcn_mfma_f32_16x16x32_bf16(ah[mi], bl[ni], acc[mi][ni], 0, 0, 0);
                    acc[mi][ni] = __builtin_amdgcn_mfma_f32_16x16x32_bf16(al[mi], bh[ni], acc[mi][ni], 0, 0, 0);
                }
            __syncthreads();
        }
#pragma unroll
        for (int mi = 0; mi < 4; ++mi)
#pragma unroll
            for (int ni = 0; ni < 4; ++ni)
#pragma unroll
                for (int r = 0; r < 4; ++r) {
                    int m = bm + wr + mi * 16 + lr + r;
                    int n = bn + wc + ni * 16 + lm;
                    int b_ = m / Ss, s_ = m % Ss;
                    int h_ = n / HDd, d_ = n % HDd;
                    C[(size_t)((b_ * NHh + h_) * Ss + s_) * HDd + d_] = acc[mi][ni][r];
                }
    } else {
        for (int k0 = 0; k0 < K; k0 += 32) {
#pragma unroll
            for (int l = 0; l < 2; ++l) {
                int L = tid + l * 256;
                int row = L >> 2, c8 = (L & 3) * 8;
                gload16(&hsh[(size_t)(bm + row) * K + k0 + c8], &AsH[L * 8]);
                gload16(&wvt[(size_t)(bn + row) * K + k0 + c8], &BsH[L * 8]);
            }
            __syncthreads();
            short8 af[4], bf[4];
#pragma unroll
            for (int mi = 0; mi < 4; ++mi) af[mi] = *(short8*)&AsH[(wr + mi * 16 + lm) * 32 + lk];
#pragma unroll
            for (int ni = 0; ni < 4; ++ni) bf[ni] = *(short8*)&BsH[(wc + ni * 16 + lm) * 32 + lk];
#pragma unroll
            for (int mi = 0; mi < 4; ++mi)
#pragma unroll
                for (int ni = 0; ni < 4; ++ni)
                    acc[mi][ni] = __builtin_amdgcn_mfma_f32_16x16x32_bf16(af[mi], bf[ni], acc[mi][ni], 0, 0, 0);
            __syncthreads();
        }
#pragma unroll
        for (int mi = 0; mi < 4; ++mi)
#pragma unroll
            for (int ni = 0; ni < 4; ++ni)
#pragma unroll
                for (int r = 0; r < 4; ++r) {
                    int m = bm + wr + mi * 16 + lr + r;
                    int n = bn + wc + ni * 16 + lm;
                    int b_ = m / Ss, s_ = m % Ss;
                    int h_ = n / HDd, d_ = n % HDd;
                    vf[(size_t)((b_ * NHh + h_) * Ss + s_) * HDd + d_] = acc[mi][ni][r];
                }
    }
}

// ---------------------------------------------------------------------------
// Single-bf16 MFMA GEMM (wo): C = A @ Bt^T, 128x64 tile (2 blocks/CU).
// ---------------------------------------------------------------------------
__global__ __launch_bounds__(256) void gemm_bf16t(const unsigned short* __restrict__ A,
                                                  const unsigned short* __restrict__ Bt,
                                                  float* __restrict__ C,
                                                  int M, int N, int K)
{
    __shared__ unsigned short As[128 * 32];
    __shared__ unsigned short Bs[64 * 32];
    const int tid = threadIdx.x;
    const int bm = blockIdx.y * 128, bn = blockIdx.x * 64;
    const int lane = tid & 63, wid = tid >> 6;
    const int wr = (wid >> 1) * 64, wc = (wid & 1) * 32;
    const int lm = lane & 15, lk = (lane >> 4) * 8;

    f32x4 acc[4][2];
#pragma unroll
    for (int mi = 0; mi < 4; ++mi)
#pragma unroll
        for (int ni = 0; ni < 2; ++ni) acc[mi][ni] = 0.0f;

    for (int k0 = 0; k0 < K; k0 += 32) {
#pragma unroll
        for (int l = 0; l < 2; ++l) {
            int L = tid + l * 256;
            int row = L >> 2, c8 = (L & 3) * 8;
            gload16(&A[(size_t)(bm + row) * K + k0 + c8], &As[L * 8]);
        }
        {
            int row = tid >> 2, c8 = (tid & 3) * 8;
            gload16(&Bt[(size_t)(bn + row) * K + k0 + c8], &Bs[tid * 8]);
        }
        __syncthreads();
        short8 af[4], bf[2];
#pragma unroll
        for (int mi = 0; mi < 4; ++mi) af[mi] = *(short8*)&As[(wr + mi * 16 + lm) * 32 + lk];
#pragma unroll
        for (int ni = 0; ni < 2; ++ni) bf[ni] = *(short8*)&Bs[(wc + ni * 16 + lm) * 32 + lk];
#pragma unroll
        for (int mi = 0; mi < 4; ++mi)
#pragma unroll
            for (int ni = 0; ni < 2; ++ni)
                acc[mi][ni] = __builtin_amdgcn_mfma_f32_16x16x32_bf16(af[mi], bf[ni], acc[mi][ni], 0, 0, 0);
        __syncthreads();
    }
    const int lr = (lane >> 4) * 4;  // C/D: col=lane&15, row=(lane>>4)*4+reg
#pragma unroll
    for (int mi = 0; mi < 4; ++mi)
#pragma unroll
        for (int ni = 0; ni < 2; ++ni)
#pragma unroll
            for (int r = 0; r < 4; ++r) {
                int m = bm + wr + mi * 16 + lr + r;
                int n = bn + wc + ni * 16 + lm;
                C[(size_t)m * N + n] = acc[mi][ni][r];
            }
}

// ---------------------------------------------------------------------------
// RoPE (fp32 math) -> split bf16 q,k (hi/lo). 64 contiguous lanes x 2B =
// 128B per store instruction — fully coalesced (R8 lesson).
// ---------------------------------------------------------------------------
__global__ __launch_bounds__(64) void rope_qk_split(const float* __restrict__ q,
                                                    const float* __restrict__ k,
                                                    unsigned short* __restrict__ qh,
                                                    unsigned short* __restrict__ ql,
                                                    unsigned short* __restrict__ kh,
                                                    unsigned short* __restrict__ kl)
{
    int idx = blockIdx.x;          // bh*S + s
    int s = idx % Ss;
    int d = threadIdx.x;           // 0..63
    float inv = powf(10000.0f, -2.0f * (float)d / 128.0f);
    float fr = (float)s * inv;
    float c = cosf(fr), sn = sinf(fr);
    size_t base = (size_t)idx * HDd;
    float q1 = q[base + d], q2 = q[base + d + 64];
    float k1 = k[base + d], k2 = k[base + d + 64];
    float qa = q1 * c - q2 * sn, qbv = q2 * c + q1 * sn;
    float ka = k1 * c - k2 * sn, kbv = k2 * c + k1 * sn;
    unsigned short h;
    h = f2b(qa);  qh[base + d]      = h; ql[base + d]      = f2b(qa  - b2f(h));
    h = f2b(qbv); qh[base + d + 64] = h; ql[base + d + 64] = f2b(qbv - b2f(h));
    h = f2b(ka);  kh[base + d]      = h; kl[base + d]      = f2b(ka  - b2f(h));
    h = f2b(kbv); kh[base + d + 64] = h; kl[base + d + 64] = f2b(kbv - b2f(h));
}

// ---------------------------------------------------------------------------
// attn = q k^T / sqrt(HD) via split-bf16 MFMA, causal mask to MASKVAL.
// Staged-LDS (proven R5/R7) + diag fragment skip (R9/R10).
// ---------------------------------------------------------------------------
__global__ __launch_bounds__(256) void attn_qk_split(const unsigned short* __restrict__ qh,
                                                     const unsigned short* __restrict__ ql,
                                                     const unsigned short* __restrict__ kh,
                                                     const unsigned short* __restrict__ kl,
                                                     float* __restrict__ attn)
{
    const int bh = blockIdx.z;
    const int bm = blockIdx.y * 128, bn = blockIdx.x * 128;
    const int tid = threadIdx.x;

    if (blockIdx.x > blockIdx.y) return;  // fully above diagonal: never read
    const bool diag = (blockIdx.x == blockIdx.y);

    float* C = attn + (size_t)bh * Ss * Ss;
    const size_t hb = (size_t)bh * Ss * HDd;
    const unsigned short* Ah = qh + hb;
    const unsigned short* Al = ql + hb;
    const unsigned short* Bh = kh + hb;
    const unsigned short* Bl = kl + hb;

    __shared__ unsigned short AsH[128 * 32], AsL[128 * 32];
    __shared__ unsigned short BsH[128 * 32], BsL[128 * 32];
    const int lane = tid & 63, wid = tid >> 6;
    const int wr = (wid >> 1) * 64, wc = (wid & 1) * 64;
    const int lm = lane & 15, lk = (lane >> 4) * 8;

    f32x4 acc[4][4];
#pragma unroll
    for (int mi = 0; mi < 4; ++mi)
#pragma unroll
        for (int ni = 0; ni < 4; ++ni) acc[mi][ni] = 0.0f;

    for (int k0 = 0; k0 < HDd; k0 += 32) {
#pragma unroll
        for (int l = 0; l < 2; ++l) {
            int L = tid + l * 256;
            int row = L >> 2, c8 = (L & 3) * 8;
            size_t ga = (size_t)(bm + row) * HDd + k0 + c8;
            size_t gb = (size_t)(bn + row) * HDd + k0 + c8;
            gload16(&Ah[ga], &AsH[L * 8]);
            gload16(&Al[ga], &AsL[L * 8]);
            gload16(&Bh[gb], &BsH[L * 8]);
            gload16(&Bl[gb], &BsL[L * 8]);
        }
        __syncthreads();
        short8 ah[4], al[4], bh2[4], bl2[4];
#pragma unroll
        for (int mi = 0; mi < 4; ++mi) {
            ah[mi] = *(short8*)&AsH[(wr + mi * 16 + lm) * 32 + lk];
            al[mi] = *(short8*)&AsL[(wr + mi * 16 + lm) * 32 + lk];
        }
#pragma unroll
        for (int ni = 0; ni < 4; ++ni) {
            bh2[ni] = *(short8*)&BsH[(wc + ni * 16 + lm) * 32 + lk];
            bl2[ni] = *(short8*)&BsL[(wc + ni * 16 + lm) * 32 + lk];
        }
#pragma unroll
        for (int mi = 0; mi < 4; ++mi)
#pragma unroll
            for (int ni = 0; ni < 4; ++ni) {
                if (diag && (wc + ni * 16 > wr + mi * 16 + 15)) continue; // acc unused (masked)
                acc[mi][ni] = __builtin_amdgcn_mfma_f32_16x16x32_bf16(ah[mi], bh2[ni], acc[mi][ni], 0, 0, 0);
                acc[mi][ni] = __builtin_amdgcn_mfma_f32_16x16x32_bf16(ah[mi], bl2[ni], acc[mi][ni], 0, 0, 0);
                acc[mi][ni] = __builtin_amdgcn_mfma_f32_16x16x32_bf16(al[mi], bh2[ni], acc[mi][ni], 0, 0, 0);
            }
        __syncthreads();
    }
    const float scale = 0.08838834764831845f;  // 1/sqrt(128)
    const int lr = (lane >> 4) * 4;
#pragma unroll
    for (int mi = 0; mi < 4; ++mi)
#pragma unroll
        for (int ni = 0; ni < 4; ++ni)
#pragma unroll
            for (int r = 0; r < 4; ++r) {
                int sq = bm + wr + mi * 16 + lr + r;
                int sk = bn + wc + ni * 16 + lm;
                C[(size_t)sq * Ss + sk] = (sk <= sq) ? acc[mi][ni][r] * scale : MASKVAL;
            }
}

// ---------------------------------------------------------------------------
// Row softmax IN PLACE with causal load-skip. Inactive lanes write zeros —
// REQUIRED: the scan/pv read 256-col chunks / k-tiles past the diagonal.
// ---------------------------------------------------------------------------
__global__ __launch_bounds__(256) void softmax_rows(float* __restrict__ attn)
{
    int row = blockIdx.x;
    int r = row & (Ss - 1);
    float4* a4 = (float4*)(attn + (size_t)row * Ss);
    int tid = threadIdx.x;
    bool act = (tid * 4 <= r);
    float4 x = make_float4(MASKVAL, MASKVAL, MASKVAL, MASKVAL);
    if (act) x = a4[tid];
    float m = fmaxf(fmaxf(x.x, x.y), fmaxf(x.z, x.w));
#pragma unroll
    for (int off = 32; off; off >>= 1) m = fmaxf(m, __shfl_xor(m, off));
    __shared__ float red[4];
    if ((tid & 63) == 0) red[tid >> 6] = m;
    __syncthreads();
    float mm = fmaxf(fmaxf(red[0], red[1]), fmaxf(red[2], red[3]));
    float e0 = expf(x.x - mm), e1 = expf(x.y - mm);
    float e2 = expf(x.z - mm), e3 = expf(x.w - mm);
    float s = e0 + e1 + e2 + e3;
#pragma unroll
    for (int off = 32; off; off >>= 1) s += __shfl_xor(s, off);
    __shared__ float red2[4];
    if ((tid & 63) == 0) red2[tid >> 6] = s;
    __syncthreads();
    float inv = 1.0f / (red2[0] + red2[1] + red2[2] + red2[3]);
    a4[tid] = make_float4(e0 * inv, e1 * inv, e2 * inv, e3 * inv);
}

// ---------------------------------------------------------------------------
// DPP cross-lane helpers (VALU-latency, no LDS pipe).
// ---------------------------------------------------------------------------
template<int CTRL>
__device__ __forceinline__ int dpp_i(int x) {
    return __builtin_amdgcn_update_dpp(0, x, CTRL, 0xF, 0xF, true);
}
__device__ __forceinline__ float wave_sum64(float x) {
    x += __int_as_float(dpp_i<0xB1>(__float_as_int(x)));
    x += __int_as_float(dpp_i<0x4E>(__float_as_int(x)));
    x += __int_as_float(dpp_i<0x141>(__float_as_int(x)));
    x += __int_as_float(dpp_i<0x140>(__float_as_int(x)));
    int xi = __float_as_int(x);
    float a = __int_as_float(__builtin_amdgcn_readlane(xi, 0));
    float b = __int_as_float(__builtin_amdgcn_readlane(xi, 16));
    float c = __int_as_float(__builtin_amdgcn_readlane(xi, 32));
    float d = __int_as_float(__builtin_amdgcn_readlane(xi, 48));
    return (a + c) + (b + d);
}

// 64-bit packed-key (value<<32 | index) helpers: lexicographic min == exact
// float-min with first-index tie-break (values are non-negative floats).
__device__ __forceinline__ unsigned long long u64min(unsigned long long a, unsigned long long b) {
    return a < b ? a : b;
}
template<int CTRL>
__device__ __forceinline__ unsigned long long dpp64(unsigned long long x) {
    int lo = (int)(unsigned)x;
    int hi = (int)(unsigned)(x >> 32);
    unsigned l2 = (unsigned)dpp_i<CTRL>(lo);
    unsigned h2 = (unsigned)dpp_i<CTRL>(hi);
    return ((unsigned long long)h2 << 32) | (unsigned long long)l2;
}
__device__ __forceinline__ unsigned long long wave_min64k(unsigned long long x) {
    x = u64min(x, dpp64<0xB1>(x));
    x = u64min(x, dpp64<0x4E>(x));
    x = u64min(x, dpp64<0x141>(x));
    x = u64min(x, dpp64<0x140>(x));
    int lo = (int)(unsigned)x;
    int hi = (int)(unsigned)(x >> 32);
    unsigned long long a = ((unsigned long long)(unsigned)__builtin_amdgcn_readlane(hi, 0)  << 32) |
                           (unsigned long long)(unsigned)__builtin_amdgcn_readlane(lo, 0);
    unsigned long long b = ((unsigned long long)(unsigned)__builtin_amdgcn_readlane(hi, 16) << 32) |
                           (unsigned long long)(unsigned)__builtin_amdgcn_readlane(lo, 16);
    unsigned long long c = ((unsigned long long)(unsigned)__builtin_amdgcn_readlane(hi, 32) << 32) |
                           (unsigned long long)(unsigned)__builtin_amdgcn_readlane(lo, 32);
    unsigned long long d = ((unsigned long long)(unsigned)__builtin_amdgcn_readlane(hi, 48) << 32) |
                           (unsigned long long)(unsigned)__builtin_amdgcn_readlane(lo, 48);
    return u64min(u64min(a, b), u64min(c, d));
}

__device__ __forceinline__ float f4c(float4 v, int i) {
    return i == 0 ? v.x : (i == 1 ? v.y : (i == 2 ? v.z : v.w));
}

// ---------------------------------------------------------------------------
// A2S sequential scan v5 (proven 390 us): single wave, branchless, causal
// chunk gating via template NC phases, float mf mask, packed u64 argmin.
// ---------------------------------------------------------------------------
template<int NC, int NCL>
__device__ __forceinline__ void scan_step(int t, int lane,
                                          const float4* __restrict__ A4,
                                          unsigned char* __restrict__ KP,
                                          float4 (&rb)[4],
                                          float (&sel)[4][4],
                                          float (&mf)[4][4])
{
    const float INFv = __int_as_float(0x7f800000);
    // snapshot row t
    float4 a[NC];
#pragma unroll
    for (int jj = 0; jj < NC; ++jj) a[jj] = rb[jj];
    // prefetch row t+4 (clamped), NCL chunks (one lookahead chunk past NC)
    int tp = t + 4; if (tp > Ss - 1) tp = Ss - 1;
#pragma unroll
    for (int jj = 0; jj < NCL; ++jj) rb[jj] = A4[tp * 256 + jj * 64 + lane];

    // masked row sum — identical add order to v4 (skipped chunks added 0.0)
    float lsum = 0.0f;
#pragma unroll
    for (int jj = 0; jj < NC; ++jj) {
        float c0 = a[jj].x * mf[jj][0], c1 = a[jj].y * mf[jj][1];
        float c2 = a[jj].z * mf[jj][2], c3 = a[jj].w * mf[jj][3];
        lsum += (c0 + c1) + (c2 + c3);
    }
    float tot = wave_sum64(lsum);
    float inv = 1.0f / tot;

    const int local = t - RBc;
    const int base = lane * 4;
    const bool ge = (base >= SBc);   // SBc%4==0 -> i-independent

    // sel update + windowed argmin via packed (value,index) keys
    unsigned long long kmin = 0xFFFFFFFFFFFFFFFFull;
#pragma unroll
    for (int jj = 0; jj < NC; ++jj) {
        unsigned long long kk[4];
#pragma unroll
        for (int i = 0; i < 4; ++i) {
            float sv = fmaf(FFf, sel[jj][i], f4c(a[jj], i) * inv);
            sel[jj][i] = sv;
            int s = jj * 256 + base + i;
            bool win = (s <= local) && (jj > 0 || ge);
            unsigned hi = win ? __float_as_uint(sv) : 0x7f800000u;
            kk[i] = ((unsigned long long)hi << 32) | (unsigned long long)(unsigned)s;
        }
        unsigned long long cm = u64min(u64min(kk[0], kk[1]), u64min(kk[2], kk[3]));
        kmin = u64min(kmin, cm);
    }
    kmin = wave_min64k(kmin);
    const int besti = (int)(unsigned)(kmin & 0xFFFFFFFFull);

    // evict + mask update
#pragma unroll
    for (int jj = 0; jj < NC; ++jj)
#pragma unroll
        for (int i = 0; i < 4; ++i) {
            int s = jj * 256 + base + i;
            bool e = (s == besti);
            sel[jj][i] = e ? INFv : sel[jj][i];
            mf[jj][i]  = e ? 0.0f : mf[jj][i];
        }

    // keep row t+1 (chunks 0..NC-1; scores are exactly 0 above, don't-care)
    uchar4* kp4 = (uchar4*)(KP + (size_t)(t + 1) * Ss);
#pragma unroll
    for (int jj = 0; jj < NC; ++jj) {
        uchar4 kb;
        kb.x = (unsigned char)mf[jj][0];
        kb.y = (unsigned char)mf[jj][1];
        kb.z = (unsigned char)mf[jj][2];
        kb.w = (unsigned char)mf[jj][3];
        kp4[jj * 64 + lane] = kb;
    }
}

__global__ __launch_bounds__(64) void scan_kernel5(const float* __restrict__ scores,
                                                   unsigned char* __restrict__ keep)
{
    int bh = blockIdx.x;
    int lane = threadIdx.x;
    const float4* A4 = (const float4*)(scores + (size_t)bh * Ss * Ss);
    unsigned char* KP = keep + (size_t)bh * Ss * Ss;

    float sel[4][4];
    float mf[4][4];
#pragma unroll
    for (int jj = 0; jj < 4; ++jj)
#pragma unroll
        for (int i = 0; i < 4; ++i) { sel[jj][i] = 0.0f; mf[jj][i] = 1.0f; }

    // ---- warmup rows 0..162: chunk 0 only (rows <163 are zero beyond col 162) ----
    float4 w0 = A4[0 * 256 + lane];
    float4 w1 = A4[1 * 256 + lane];
    float4 w2 = A4[2 * 256 + lane];
    float4 w3 = A4[3 * 256 + lane];
#define WSTEP(W, NEXT)                                                       \
    do {                                                                     \
        float4 _a = W;                                                       \
        W = A4[(NEXT) * 256 + lane];                                         \
        sel[0][0] = fmaf(FFf, sel[0][0], _a.x);                              \
        sel[0][1] = fmaf(FFf, sel[0][1], _a.y);                              \
        sel[0][2] = fmaf(FFf, sel[0][2], _a.z);                              \
        sel[0][3] = fmaf(FFf, sel[0][3], _a.w);                              \
    } while (0)
    for (int r = 0; r < 160; r += 4) {
        WSTEP(w0, r + 4); WSTEP(w1, r + 5); WSTEP(w2, r + 6); WSTEP(w3, r + 7);
    }
#undef WSTEP
    {   // rows 160..162 tail (w3 = row 163 discarded)
        float4 tl[3] = { w0, w1, w2 };
#pragma unroll
        for (int u = 0; u < 3; ++u) {
            sel[0][0] = fmaf(FFf, sel[0][0], tl[u].x);
            sel[0][1] = fmaf(FFf, sel[0][1], tl[u].y);
            sel[0][2] = fmaf(FFf, sel[0][2], tl[u].z);
            sel[0][3] = fmaf(FFf, sel[0][3], tl[u].w);
        }
    }

    // ---- init scan prefetch: rows 163..166, chunk 0 ----
    float4 rb[4][4];
#pragma unroll
    for (int slot = 0; slot < 4; ++slot)
        rb[slot][0] = A4[(163 + slot) * 256 + lane];

    // ---- phased scan: t = 163..1022 (keep rows 164..1023) ----
    for (int t0 = 163; t0 < 255; t0 += 4) {           // 92 steps, NC=1
        scan_step<1, 2>(t0 + 0, lane, A4, KP, rb[0], sel, mf);
        scan_step<1, 2>(t0 + 1, lane, A4, KP, rb[1], sel, mf);
        scan_step<1, 2>(t0 + 2, lane, A4, KP, rb[2], sel, mf);
        scan_step<1, 2>(t0 + 3, lane, A4, KP, rb[3], sel, mf);
    }
    for (int t0 = 255; t0 < 511; t0 += 4) {           // 256 steps, NC=2
        scan_step<2, 3>(t0 + 0, lane, A4, KP, rb[0], sel, mf);
        scan_step<2, 3>(t0 + 1, lane, A4, KP, rb[1], sel, mf);
        scan_step<2, 3>(t0 + 2, lane, A4, KP, rb[2], sel, mf);
        scan_step<2, 3>(t0 + 3, lane, A4, KP, rb[3], sel, mf);
    }
    for (int t0 = 511; t0 < 767; t0 += 4) {           // 256 steps, NC=3
        scan_step<3, 4>(t0 + 0, lane, A4, KP, rb[0], sel, mf);
        scan_step<3, 4>(t0 + 1, lane, A4, KP, rb[1], sel, mf);
        scan_step<3, 4>(t0 + 2, lane, A4, KP, rb[2], sel, mf);
        scan_step<3, 4>(t0 + 3, lane, A4, KP, rb[3], sel, mf);
    }
    for (int t0 = 767; t0 < 1023; t0 += 4) {          // 256 steps, NC=4
        scan_step<4, 4>(t0 + 0, lane, A4, KP, rb[0], sel, mf);
        scan_step<4, 4>(t0 + 1, lane, A4, KP, rb[1], sel, mf);
        scan_step<4, 4>(t0 + 2, lane, A4, KP, rb[2], sel, mf);
        scan_step<4, 4>(t0 + 3, lane, A4, KP, rb[3], sel, mf);
    }
}

// ---------------------------------------------------------------------------
// PV via split-bf16 MFMA: ctx = (keep.*P) @ V / rowsum(keep.*P).
// 128x64 tile, 4 waves, acc[4][2]. P masked + split-converted during LDS
// staging; B = vth/vtl [d][k]; rowsum via ones-B-fragment MFMA (exact-ish
// deterministic Σph + Σpl). Drops pl*vl (~2^-16 rel) — fp32-grade like the
// other split GEMMs. Epilogue ushort stores are 32B runs per 16-lane group.
// ---------------------------------------------------------------------------
__global__ __launch_bounds__(256) void pv_mfma(const float* __restrict__ scores,
                                               const unsigned char* __restrict__ keep,
                                               const unsigned short* __restrict__ vth,
                                               const unsigned short* __restrict__ vtl,
                                               unsigned short* __restrict__ ctxb)
{
    __shared__ unsigned short AsH[128 * 32], AsL[128 * 32];
    __shared__ unsigned short BsH[64 * 32],  BsL[64 * 32];
    const int bh = blockIdx.z;
    const int b_ = bh / NHh, h_ = bh % NHh;
    const float* P = scores + (size_t)bh * Ss * Ss;
    const unsigned char* KPm = keep + (size_t)bh * Ss * Ss;
    const unsigned short* Vh = vth + (size_t)bh * HDd * Ss;
    const unsigned short* Vl = vtl + (size_t)bh * HDd * Ss;
    const int bm = blockIdx.y * 128, bn = blockIdx.x * 64;
    const int tid = threadIdx.x;
    const int lane = tid & 63, wid = tid >> 6;
    const int wr = (wid >> 1) * 64, wc = (wid & 1) * 32;
    const int lm = lane & 15, lk = (lane >> 4) * 8;

    short8 ones;
#pragma unroll
    for (int i = 0; i < 8; ++i) ones[i] = (short)0x3F80;   // bf16 1.0

    f32x4 acc[4][2];
    f32x4 rsa[4];
#pragma unroll
    for (int mi = 0; mi < 4; ++mi) {
        rsa[mi] = 0.0f;
#pragma unroll
        for (int ni = 0; ni < 2; ++ni) acc[mi][ni] = 0.0f;
    }

    const int kend = bm + 128;   // causal: rows bm..bm+127 need k <= bm+127
    for (int k0 = 0; k0 < kend; k0 += 32) {
        // stage A: P[128 rows][32 k] masked -> split bf16
#pragma unroll
        for (int l = 0; l < 4; ++l) {
            int idx = tid + l * 256;           // 0..1023 float4 slots
            int row = idx >> 3, c4 = (idx & 7) * 4;
            size_t ga = (size_t)(bm + row) * Ss + k0 + c4;
            float4 p4 = *(const float4*)&P[ga];
            if (bm + row > CBc) {
                uchar4 kb = *(const uchar4*)&KPm[ga];
                if (!kb.x) p4.x = 0.0f;
                if (!kb.y) p4.y = 0.0f;
                if (!kb.z) p4.z = 0.0f;
                if (!kb.w) p4.w = 0.0f;
            }
            ushort4 h, l2;
            h.x = f2b(p4.x); l2.x = f2b(p4.x - b2f(h.x));
            h.y = f2b(p4.y); l2.y = f2b(p4.y - b2f(h.y));
            h.z = f2b(p4.z); l2.z = f2b(p4.z - b2f(h.z));
            h.w = f2b(p4.w); l2.w = f2b(p4.w - b2f(h.w));
            *(ushort4*)&AsH[row * 32 + c4] = h;
            *(ushort4*)&AsL[row * 32 + c4] = l2;
        }
        // stage B: V^T[64 d][32 k] hi/lo
#pragma unroll
        for (int l = 0; l < 2; ++l) {
            int idx = tid + l * 256;           // 0..511 ushort4 slots
            int row = idx >> 3, c4 = (idx & 7) * 4;
            size_t gb = (size_t)(bn + row) * Ss + k0 + c4;
            *(ushort4*)&BsH[row * 32 + c4] = *(const ushort4*)&Vh[gb];
            *(ushort4*)&BsL[row * 32 + c4] = *(const ushort4*)&Vl[gb];
        }
        __syncthreads();
        short8 ah[4], al[4], bhf[2], blf[2];
#pragma unroll
        for (int mi = 0; mi < 4; ++mi) {
            ah[mi] = *(short8*)&AsH[(wr + mi * 16 + lm) * 32 + lk];
            al[mi] = *(short8*)&AsL[(wr + mi * 16 + lm) * 32 + lk];
        }
#pragma unroll
        for (int ni = 0; ni < 2; ++ni) {
            bhf[ni] = *(short8*)&BsH[(wc + ni * 16 + lm) * 32 + lk];
            blf[ni] = *(short8*)&BsL[(wc + ni * 16 + lm) * 32 + lk];
        }
#pragma unroll
        for (int mi = 0; mi < 4; ++mi) {
            rsa[mi] = __builtin_amdgcn_mfma_f32_16x16x32_bf16(ah[mi], ones, rsa[mi], 0, 0, 0);
            rsa[mi] = __builtin_amdgcn_mfma_f32_16x16x32_bf16(al[mi], ones, rsa[mi], 0, 0, 0);
#pragma unroll
            for (int ni = 0; ni < 2; ++ni) {
                acc[mi][ni] = __builtin_amdgcn_mfma_f32_16x16x32_bf16(ah[mi], bhf[ni], acc[mi][ni], 0, 0, 0);
                acc[mi][ni] = __builtin_amdgcn_mfma_f32_16x16x32_bf16(ah[mi], blf[ni], acc[mi][ni], 0, 0, 0);
                acc[mi][ni] = __builtin_amdgcn_mfma_f32_16x16x32_bf16(al[mi], bhf[ni], acc[mi][ni], 0, 0, 0);
            }
        }
        __syncthreads();
    }
    const int lr = (lane >> 4) * 4;
#pragma unroll
    for (int mi = 0; mi < 4; ++mi)
#pragma unroll
        for (int r = 0; r < 4; ++r) {
            int sq = bm + wr + mi * 16 + lr + r;
            float inv = 1.0f / rsa[mi][r];   // rowsum > 0 (diag always kept)
            size_t ob = (size_t)(b_ * Ss + sq) * HIDd + h_ * HDd;
#pragma unroll
            for (int ni = 0; ni < 2; ++ni) {
                int d = bn + wc + ni * 16 + lm;
                ctxb[ob + d] = f2b(acc[mi][ni][r] * inv);
            }
        }
}

// ---------------------------------------------------------------------------
extern "C" void kernel_launch(void* const* d_in, const int* in_sizes, int n_in,
                              void* d_out, int out_size, void* d_ws, size_t ws_size,
                              hipStream_t stream)
{
    const float* hs = (const float*)d_in[0];
    const float* wq = (const float*)d_in[1];
    const float* wk = (const float*)d_in[2];
    const float* wv = (const float*)d_in[3];
    const float* wo = (const float*)d_in[4];
    float* out = (float*)d_out;

    float* ws = (float*)d_ws;
    size_t off = 0;
    float* qf   = ws + off; off += (size_t)NBH * Ss * HDd;   // 16 MB (reused: ctxb)
    float* kf   = ws + off; off += (size_t)NBH * Ss * HDd;   // 16 MB (reused: vth/vtl)
    float* vf   = ws + off; off += (size_t)NBH * Ss * HDd;   // 16 MB
    float* attn = ws + off; off += (size_t)NBH * Ss * Ss;    // 128 MB
    unsigned char* keep = (unsigned char*)(ws + off); off += (size_t)NBH * Ss * Ss / 4; // 32 MB
    unsigned short* wot = (unsigned short*)(ws + off); off += (size_t)HIDd * HIDd / 2;  // 8 MB

    // Transients overlaid on attn (dead before attn is written). 8 MB = 2M floats each.
    unsigned short* hsh  = (unsigned short*)(attn);
    unsigned short* hsl  = (unsigned short*)(attn + 2u * 1024 * 1024);
    unsigned short* wqth = (unsigned short*)(attn + 4u * 1024 * 1024);
    unsigned short* wqtl = (unsigned short*)(attn + 6u * 1024 * 1024);
    unsigned short* wkth = (unsigned short*)(attn + 8u * 1024 * 1024);
    unsigned short* wktl = (unsigned short*)(attn + 10u * 1024 * 1024);
    unsigned short* wvt  = (unsigned short*)(attn + 12u * 1024 * 1024);
    // q/k split bf16 overlaid on keep (keep written only by the scan, later):
    unsigned short* qh = (unsigned short*)keep;
    unsigned short* ql = (unsigned short*)(keep + 8u * 1024 * 1024);
    unsigned short* kh = (unsigned short*)(keep + 16u * 1024 * 1024);
    unsigned short* kl = (unsigned short*)(keep + 24u * 1024 * 1024);
    // vth/vtl overlay kf (kf dead after rope); ctxb overlays qf (dead after rope):
    unsigned short* vth = (unsigned short*)kf;
    unsigned short* vtl = (unsigned short*)kf + (size_t)NBH * HDd * Ss;
    unsigned short* ctxb = (unsigned short*)qf;

    dim3 blk(256);
    const int M = Bb * Ss;  // 2048

    // hs -> split bf16
    conv_split<<<dim3((M * HIDd / 4 + 255) / 256), blk, 0, stream>>>(hs, hsh, hsl, M * HIDd / 4);

    // all 4 weight transposes in one launch
    tconv_all<<<dim3(HIDd / 64, HIDd / 64, 4), blk, 0, stream>>>(
        wq, wk, wv, wo, wqth, wqtl, wkth, wktl, wvt, wot);

    // merged q/k/v projection (768 blocks -> 3 blocks/CU)
    gemm_qkv<<<dim3(48, M / 128), blk, 0, stream>>>(
        hsh, hsl, wqth, wqtl, wkth, wktl, wvt, qf, kf, vf);

    // RoPE (fp32 math) -> split bf16 q,k (coalesced 128B ushort stores)
    rope_qk_split<<<dim3(NBH * Ss), dim3(64), 0, stream>>>(qf, kf, qh, ql, kh, kl);

    // V transpose + split convert: vf[s][d] -> vth/vtl[d][s] (overlays dead kf)
    vtrans<<<dim3(HDd / 64, Ss / 64, NBH), blk, 0, stream>>>(vf, vth, vtl);

    // QK^T (split-precision MFMA, staged LDS) + causal mask + diag frag skip
    attn_qk_split<<<dim3(Ss / 128, Ss / 128, NBH), blk, 0, stream>>>(qh, ql, kh, kl, attn);

    // attn -> normalized scores, in place (causal load-skip)
    softmax_rows<<<dim3(NROWS), blk, 0, stream>>>(attn);

    // sequential A2S scan -> keep mask (v5, proven)
    scan_kernel5<<<dim3(NBH), dim3(64), 0, stream>>>(attn, keep);

    // fused mask + renorm + PV via split-bf16 MFMA
    pv_mfma<<<dim3(HDd / 64, Ss / 128, NBH), blk, 0, stream>>>(attn, keep, vth, vtl, ctxb);

    // out = ctx @ wo (bf16 MFMA, fp32 out) — 128x64 tile, 2 blocks/CU
    gemm_bf16t<<<dim3(HIDd / 64, M / 128), blk, 0, stream>>>(ctxb, wot, out, M, HIDd, HIDd);
}